// Round 1
// 333.321 us; speedup vs baseline: 1.1465x; 1.1465x over previous
//
#include <hip/hip_runtime.h>
#include <hip/hip_bf16.h>
#include <math.h>

// ============================================================================
// EquiGroupSamplingC8 (f32 I/O confirmed by runtime sniff; bf16 path retained).
// R5: GEMM2 retiled to 32x32x16 MFMA BM128/BN64/BK64 with XOR-swizzled LDS.
// R6: K1/K2 (DP Wigner setup) rebuilt on fixed 13x13 padded matrices:
//     all matmul loops compile-time (full unroll -> pipelined ds_read_b64),
//     192-thread blocks (1 elem/thread), parallel norm row-sums, hoisted
//     sqrt ladder coefficients. exps is stride-13 everywhere now.
// ============================================================================

typedef __attribute__((ext_vector_type(8))) short bf16x8;
typedef __attribute__((ext_vector_type(4))) float f32x4;
typedef __attribute__((ext_vector_type(16))) float f32x16;

__device__ const int c_offs[8] = {0, 1, 10, 35, 84, 165, 286, 455};

struct SetupArgs {
  double angA[16];              // 2*pi*k/16 (alpha and gamma grid)
  double angB[8];               // arccos(GL8 nodes)
  double c8a[8], c8b[8], c8g[8];
};
struct QWArgs { double wb[8]; };
struct W2Ptrs { const void* p[7]; };

__device__ __forceinline__ float bf2f(unsigned short u) {
  union { unsigned int i; float f; } v; v.i = ((unsigned int)u) << 16; return v.f;
}
__device__ __forceinline__ unsigned short f2bf(float f) {
  union { float f; unsigned int i; } v; v.f = f;
  unsigned int r = v.i + 0x7fffu + ((v.i >> 16) & 1u);
  return (unsigned short)(r >> 16);
}
__device__ __forceinline__ float in_val(const void* p, size_t i, int isf) {
  return isf ? ((const float*)p)[i] : bf2f(((const unsigned short*)p)[i]);
}
__device__ __forceinline__ void gl_lds16(const void* g, void* lds) {
  __builtin_amdgcn_global_load_lds(
      (const __attribute__((address_space(1))) unsigned int*)g,
      (__attribute__((address_space(3))) unsigned int*)lds, 16, 0, 0);
}

// ---------------------------------------------------------------------------
// K1: exp matrices, fixed 13x13 padded. blocks [0,336) = 7 l * 48 items;
// block 336 = dtype sniff. 192 threads, 1 element/thread, all loops unrolled.
// Padding is exact: generator B zero-padded => exp(B) = blk (+) I.
// ---------------------------------------------------------------------------
__global__ __launch_bounds__(192) void k_exps(SetupArgs args, double* exps,
                                              const void* x, int* flag) {
  __shared__ double Qr[169], Qi[169], Bm[169], R[169];
  __shared__ double coefA[13], coefB[13], rowsum[13];
  __shared__ double snorm;
  __shared__ int cnt;
  int tid = threadIdx.x;

  if (blockIdx.x == 336) {           // dtype sniff: f32 N(0,1) magnitude band
    if (tid == 0) cnt = 0;
    __syncthreads();
    if (tid < 64) {
      float v = ((const float*)x)[tid];
      float a = fabsf(v);
      int ok = (v == v) && (a > 9.0949470e-13f) && (a < 1.0995116e12f);
      atomicAdd(&cnt, ok);
    }
    __syncthreads();
    if (tid == 0) *flag = (cnt >= 32) ? 1 : 0;
    return;
  }

  int l = blockIdx.x / 48, item = blockIdx.x % 48;
  int n = 2 * l + 1;
  int e = tid;
  bool val = (e < 169);
  int r = e / 13, c = e % 13;

  if (val) { Qr[e] = 0.0; Qi[e] = 0.0; }
  __syncthreads();
  if (tid == 0) {
    const double is2 = 0.70710678118654752440;
    for (int m = -l; m <= l; m++) {
      int rr = l + m;
      if (m < 0) {
        Qr[rr * 13 + (l - m)] = is2;
        Qi[rr * 13 + (l + m)] = -is2;
      } else if (m == 0) {
        Qr[l * 13 + l] = 1.0;
      } else {
        double s = (m & 1) ? -1.0 : 1.0;
        Qr[rr * 13 + (l + m)] = s * is2;
        Qi[rr * 13 + (l - m)] = s * is2;
      }
    }
  }
  double jj = (double)l;
  if (tid < 13) {  // hoisted ladder coefficients (clamped: padded rows are *0)
    double m1 = (double)(tid - 1 - l);
    coefA[tid] = -0.5 * sqrt(fmax(jj * (jj + 1.0) - m1 * (m1 + 1.0), 0.0));
    double m2 = (double)(tid + 1 - l);
    coefB[tid] = 0.5 * sqrt(fmax(jj * (jj + 1.0) - m2 * (m2 - 1.0), 0.0));
  }
  __syncthreads();
  { // multiply by (-1j)^l
    int lm = l & 3;
    double pr = (lm == 0) ? 1.0 : (lm == 2 ? -1.0 : 0.0);
    double pi = (lm == 1) ? -1.0 : (lm == 3 ? 1.0 : 0.0);
    if (val) {
      double qr = Qr[e], qi = Qi[e];
      Qr[e] = qr * pr - qi * pi;
      Qi[e] = qr * pi + qi * pr;
    }
  }
  __syncthreads();

  double t; int axis;
  if (item < 16)      { t = args.angA[item];      axis = 1; }
  else if (item < 24) { t = args.angB[item - 16]; axis = 0; }
  else if (item < 32) { t = args.c8a[item - 24];  axis = 1; }
  else if (item < 40) { t = args.c8b[item - 32];  axis = 0; }
  else                { t = args.c8g[item - 40];  axis = 1; }

  if (val) {
    double accr = 0.0;
    if (axis == 1) {
#pragma unroll
      for (int p = 0; p < 13; p++) {
        double mp = (double)(p - l);
        double ar = Qr[p * 13 + r], ai = -Qi[p * 13 + r];
        double br = Qr[p * 13 + c], bi = Qi[p * 13 + c];
        accr += -mp * (ar * bi + ai * br);
      }
    } else {
#pragma unroll
      for (int p = 0; p < 13; p++) {
        double xr = 0.0, xi = 0.0;
        if (p > 0) {
          double v = coefA[p];
          xr += v * Qr[(p - 1) * 13 + c]; xi += v * Qi[(p - 1) * 13 + c];
        }
        if (p < 12) {
          double v = coefB[p];
          xr += v * Qr[(p + 1) * 13 + c]; xi += v * Qi[(p + 1) * 13 + c];
        }
        double ar = Qr[p * 13 + r], ai = -Qi[p * 13 + r];
        accr += ar * xr - ai * xi;
      }
    }
    Bm[e] = t * accr;
  }
  __syncthreads();
  if (tid < 13) {  // parallel row-sums for the scaling norm
    double s = 0.0;
#pragma unroll
    for (int cc = 0; cc < 13; cc++) s += fabs(Bm[tid * 13 + cc]);
    rowsum[tid] = s;
  }
  __syncthreads();
  if (tid == 0) {
    double mx = 0.0;
#pragma unroll
    for (int rr = 0; rr < 13; rr++) mx = fmax(mx, rowsum[rr]);
    int s = 0;
    while (mx > 0.5 && s < 48) { mx *= 0.5; s++; }
    snorm = (double)s;
  }
  __syncthreads();
  int sq = (int)snorm;
  double sc = 1.0;
  for (int i = 0; i < sq; i++) sc *= 0.5;
  if (val) {
    double b = Bm[e] * sc;
    Bm[e] = b;
    R[e] = b / 16.0 + ((r == c) ? 1.0 : 0.0);
  }
  __syncthreads();
  for (int k = 15; k >= 1; k--) {   // Horner: R <- Bm*R/k + I
    double acc = 0.0;
    if (val) {
#pragma unroll
      for (int p = 0; p < 13; p++) acc += Bm[r * 13 + p] * R[p * 13 + c];
    }
    __syncthreads();
    if (val) R[e] = acc / (double)k + ((r == c) ? 1.0 : 0.0);
    __syncthreads();
  }
  for (int i = 0; i < sq; i++) {    // squarings
    double acc = 0.0;
    if (val) {
#pragma unroll
      for (int p = 0; p < 13; p++) acc += R[r * 13 + p] * R[p * 13 + c];
    }
    __syncthreads();
    if (val) R[e] = acc;
    __syncthreads();
  }
  double* out = exps + (size_t)blockIdx.x * 169;
  if (val) out[e] = R[e];
  (void)n;
}

// ---------------------------------------------------------------------------
// K2: assemble (192 threads, fixed 13x13). blocks [0,3584) = (l,a,b,cgrp)
// each 4 gammas: dwt/dint; [3584,3640) = (l,ci) c8 -> c8w f32;
// [3640,4067) = feat (proj_1).
// ---------------------------------------------------------------------------
__global__ __launch_bounds__(192) void k_assemble(const double* exps, QWArgs qw,
                                                  unsigned short* dwt, float* dint,
                                                  float* c8w,
                                                  const void* traj, const void* w1l0,
                                                  const void* w1l1, float* feat,
                                                  const int* flag) {
  __shared__ double Ea[169], Eb[169], Ec[169], T1[169];
  int tid = threadIdx.x;
  int bx = blockIdx.x;

  if (bx >= 3640) {                   // ---- feat (proj_1) ----
    int isf = __builtin_amdgcn_readfirstlane(flag[0]);
    int idx = (bx - 3640) * 192 + tid;
    if (idx >= 512 * 160) return;
    int bt = idx / 160, rem = idx % 160;
    int c = rem / 10, i = rem % 10;
    float v;
    if (i == 0) {
      v = in_val(traj, bt * 10 + 9, isf) * in_val(w1l0, c, isf);
    } else {
      int ii = i - 1, w = ii / 3, m = ii % 3;
      float acc = 0.0f;
      for (int u = 0; u < 3; u++)
        acc += in_val(traj, bt * 10 + 3 * u + m, isf) *
               in_val(w1l1, c * 9 + u * 3 + w, isf);
      v = acc * 0.57735026918962576f;
    }
    feat[idx] = v;
    return;
  }

  int e = tid;
  bool valp = (e < 169);
  int r = e / 13, c = e % 13;

  if (bx >= 3584) {                   // ---- C8 points ----
    int idx = bx - 3584;
    int l = idx / 8, ci = idx % 8;
    int d = 2 * l + 1;
    const double* pa = exps + (size_t)(l * 48 + 24 + ci) * 169;
    const double* pb = exps + (size_t)(l * 48 + 32 + ci) * 169;
    const double* pc = exps + (size_t)(l * 48 + 40 + ci) * 169;
    if (valp) { Ea[e] = pa[e]; Eb[e] = pb[e]; Ec[e] = pc[e]; }
    __syncthreads();
    if (valp) {
      double acc = 0.0;
#pragma unroll
      for (int p = 0; p < 13; p++) acc += Ea[r * 13 + p] * Eb[p * 13 + c];
      T1[e] = acc;
    }
    __syncthreads();
    double scale = sqrt((double)(2 * l + 1));
    if (valp) {
      double acc = 0.0;
#pragma unroll
      for (int p = 0; p < 13; p++) acc += T1[r * 13 + p] * Ec[p * 13 + c];
      if (r < d && c < d)
        c8w[ci * 512 + c_offs[l] + r * d + c] = (float)(scale * acc);
    }
    if (l == 0) {
      for (int jz = 455 + tid; jz < 512; jz += 192)
        c8w[ci * 512 + jz] = 0.0f;
    }
    return;
  }

  // ---- grid (l, a, b, cgrp), loop 4 gammas ----
  int l = bx / 512, rem = bx % 512;
  int a = rem >> 5, b = (rem >> 2) & 7, cg = rem & 3;
  int d = 2 * l + 1;
  const double* pa = exps + (size_t)(l * 48 + a) * 169;
  const double* pb = exps + (size_t)(l * 48 + 16 + b) * 169;
  if (valp) { Ea[e] = pa[e]; Eb[e] = pb[e]; }
  __syncthreads();
  if (valp) {
    double acc = 0.0;
#pragma unroll
    for (int p = 0; p < 13; p++) acc += Ea[r * 13 + p] * Eb[p * 13 + c];
    T1[e] = acc;
  }
  double scale = sqrt((double)(2 * l + 1));
  double qwv = qw.wb[b] * (1.0 / 512.0);
  bool inblk = valp && (r < d) && (c < d);
  int j = inblk ? (c_offs[l] + r * d + c) : 0;
  const double* ctab = exps + (size_t)(l * 48) * 169;   // items [0,16) = gamma
  for (int cc = cg * 4; cc < cg * 4 + 4; cc++) {
    __syncthreads();
    if (valp) Ec[e] = ctab[(size_t)cc * 169 + e];
    __syncthreads();
    int g = a * 128 + b * 16 + cc;
    if (valp) {
      double acc = 0.0;
#pragma unroll
      for (int p = 0; p < 13; p++) acc += T1[r * 13 + p] * Ec[p * 13 + c];
      if (inblk) {
        dwt[(size_t)j * 2048 + g] = f2bf((float)(scale * acc * qwv));
        if (l == 1) dint[(size_t)(1 + r * 3 + c) * 2048 + g] = (float)(scale * acc);
        if (l == 0 && e == 0) dint[g] = (float)(scale * acc);
      }
    }
    if (l == 0) {
      for (int jz = 455 + tid; jz < 512; jz += 192)
        dwt[(size_t)jz * 2048 + g] = 0;
    }
  }
}

// ---------------------------------------------------------------------------
// K3: sig [8192][2048] bf16 = relu(feat @ D_IN^T) * sqrt(2)
// ---------------------------------------------------------------------------
__global__ __launch_bounds__(256) void k_sig(const float* feat, const float* dint,
                                             unsigned short* sig) {
  int bi = blockIdx.x >> 3;
  int g = ((blockIdx.x & 7) << 8) + threadIdx.x;
  float din[10];
#pragma unroll
  for (int i = 0; i < 10; i++) din[i] = dint[(size_t)i * 2048 + g];
  const float* fr = feat + bi * 160;
  for (int cc = 0; cc < 16; cc++) {
    float acc = 0.0f;
#pragma unroll
    for (int i = 0; i < 10; i++) acc += fr[cc * 10 + i] * din[i];
    acc = fmaxf(acc, 0.0f) * 1.41421356237309505f;
    sig[(size_t)(bi * 16 + cc) * 2048 + g] = f2bf(acc);
  }
}

// ---------------------------------------------------------------------------
// K4: E_T [512][8192] bf16: row n=g*8+i, col k=f*512+jj
// ---------------------------------------------------------------------------
__global__ __launch_bounds__(256) void k_ebuild(W2Ptrs w2, const float* c8w,
                                                unsigned short* et, const int* flag) {
  int isf = __builtin_amdgcn_readfirstlane(flag[0]);
  int idx = blockIdx.x * 256 + threadIdx.x;     // 512*16*512
  int n = idx >> 13;
  int rest = idx & 8191;
  int f = rest >> 9, jj = rest & 511;
  size_t oaddr = (size_t)n * 8192 + f * 512 + jj;
  if (jj >= 455) { et[oaddr] = 0; return; }
  int l = 0;
  while (jj >= c_offs[l + 1]) l++;
  int d = 2 * l + 1;
  int rloc = jj - c_offs[l];
  int u = rloc / d, m = rloc % d;
  int g = n >> 3, i = n & 7;
  const void* wp = w2.p[l];
  float acc = 0.0f;
  for (int w = 0; w < d; w++) {
    float wv = in_val(wp, ((size_t)(f * 64 + g) * d + u) * d + w, isf);
    acc += wv * c8w[i * 512 + c_offs[l] + w * d + m];
  }
  acc *= rsqrtf((float)(16 * d));
  et[oaddr] = f2bf(acc);
}

// ---------------------------------------------------------------------------
// K5: GEMM2: f2[8192][512] = sig[8192][2048] @ dwt^T.
// BM=128 BN=64 BK=64, 32x32x16 MFMA, XOR-swizzled LDS (phys chunk = logical
// k-chunk ^ (row&7)) to break the 128B-stride bank aliasing.
// grid 512 = 64 mt x 8 nt; 4 waves: wm = wid>>1 (64 rows), wn = wid&1 (32 cols).
// ---------------------------------------------------------------------------
__global__ __launch_bounds__(256) void k_gemm2(const unsigned short* A,
                                               const unsigned short* B,
                                               unsigned short* C) {
  __shared__ __align__(16) unsigned short As[128 * 64];
  __shared__ __align__(16) unsigned short Bs[64 * 64];
  int tid = threadIdx.x;
  int lane = tid & 63, wid = tid >> 6;
  int mt = blockIdx.x >> 3, nt = blockIdx.x & 7;
  int m0 = mt * 128, n0 = nt * 64;
  int wm = wid >> 1, wn = wid & 1;
  f32x16 acc[2];
#pragma unroll
  for (int t = 0; t < 2; t++)
#pragma unroll
    for (int r = 0; r < 16; r++) acc[t][r] = 0.0f;

  // staging: chunk id within a 256-chunk issue = tid; row r0 = tid>>3,
  // phys chunk p = tid&7 holds logical kc = p ^ (r0&7).
  int r0 = tid >> 3;
  int kcl = (tid & 7) ^ (r0 & 7);          // logical k-chunk this lane fetches
  const unsigned short* Abase = A + (size_t)m0 * 2048;
  const unsigned short* Bbase = B + (size_t)n0 * 2048;
  // fragment read addressing
  int mrow = (lane & 31);                   // within 32-tile
  int xr = lane & 7;                        // row&7 for swizzle
  int khalf = lane >> 5;                    // 0/1 -> +8 k elems

  for (int kt = 0; kt < 32; kt++) {
    int k0 = kt * 64;
#pragma unroll
    for (int i = 0; i < 4; i++)
      gl_lds16(Abase + (size_t)(i * 32 + r0) * 2048 + k0 + kcl * 8,
               &As[i * 2048 + wid * 512]);
#pragma unroll
    for (int i = 0; i < 2; i++)
      gl_lds16(Bbase + (size_t)(i * 32 + r0) * 2048 + k0 + kcl * 8,
               &Bs[i * 2048 + wid * 512]);
    __syncthreads();
#pragma unroll
    for (int q = 0; q < 4; q++) {           // K quarters of 16
      int qc = q * 2 + khalf;               // logical k-chunk [0,8)
      bf16x8 bv = *(const bf16x8*)&Bs[(wn * 32 + mrow) * 64 + (qc ^ xr) * 8];
#pragma unroll
      for (int t = 0; t < 2; t++) {
        bf16x8 av = *(const bf16x8*)&As[(wm * 64 + t * 32 + mrow) * 64 + (qc ^ xr) * 8];
        acc[t] = __builtin_amdgcn_mfma_f32_32x32x16_bf16(av, bv, acc[t], 0, 0, 0);
      }
    }
    __syncthreads();
  }
  int col = n0 + wn * 32 + (lane & 31);
#pragma unroll
  for (int t = 0; t < 2; t++)
#pragma unroll
    for (int r = 0; r < 16; r++) {
      int row = m0 + wm * 64 + t * 32 + (r & 3) + 8 * (r >> 2) + 4 * (lane >> 5);
      C[(size_t)row * 512 + col] = f2bf(acc[t][r]);
    }
}

// ---------------------------------------------------------------------------
// K6: GEMM3 split-K=8: Cp[kc][512][512] f32 = f2[512][8192] @ E (E_T staged)
// ---------------------------------------------------------------------------
__global__ __launch_bounds__(256) void k_gemm3(const unsigned short* A,
                                               const unsigned short* B, float* Cp) {
  __shared__ __align__(16) unsigned short As[64 * 32];
  __shared__ __align__(16) unsigned short Bs[128 * 32];
  int tid = threadIdx.x, lane = tid & 63, wid = tid >> 6;
  int kc = blockIdx.x >> 5;
  int mt = (blockIdx.x >> 2) & 7, nt = blockIdx.x & 3;
  int m0 = mt * 64, n0 = nt * 128;
  int wm = wid >> 1, wn = wid & 1;
  f32x4 acc[2][4];
#pragma unroll
  for (int a = 0; a < 2; a++)
#pragma unroll
    for (int b = 0; b < 4; b++) acc[a][b] = (f32x4){0.f, 0.f, 0.f, 0.f};
  int c0 = tid;
  int ar = c0 >> 2, ak = (c0 & 3) * 8;
  const unsigned short* Abase = A + (size_t)m0 * 8192 + kc * 1024;
  const unsigned short* Bbase = B + (size_t)n0 * 8192 + kc * 1024;
  int row = lane & 15, kq = (lane >> 4) * 8;
  for (int kt = 0; kt < 32; kt++) {
    int k0 = kt * 32;
    gl_lds16(Abase + (size_t)ar * 8192 + k0 + ak, &As[wid * 512]);
    gl_lds16(Bbase + (size_t)ar * 8192 + k0 + ak, &Bs[wid * 512]);
    gl_lds16(Bbase + (size_t)(ar + 64) * 8192 + k0 + ak, &Bs[2048 + wid * 512]);
    __syncthreads();
    bf16x8 af[2], bfr[4];
#pragma unroll
    for (int im = 0; im < 2; im++)
      af[im] = *(const bf16x8*)&As[(wm * 32 + im * 16 + row) * 32 + kq];
#pragma unroll
    for (int in = 0; in < 4; in++)
      bfr[in] = *(const bf16x8*)&Bs[(wn * 64 + in * 16 + row) * 32 + kq];
#pragma unroll
    for (int im = 0; im < 2; im++)
#pragma unroll
      for (int in = 0; in < 4; in++)
        acc[im][in] = __builtin_amdgcn_mfma_f32_16x16x32_bf16(af[im], bfr[in],
                                                              acc[im][in], 0, 0, 0);
    __syncthreads();
  }
  int col = lane & 15, rq = (lane >> 4) * 4;
  float* out = Cp + (size_t)kc * 262144;
#pragma unroll
  for (int im = 0; im < 2; im++)
#pragma unroll
    for (int in = 0; in < 4; in++)
#pragma unroll
      for (int r = 0; r < 4; r++) {
        int rr = m0 + wm * 32 + im * 16 + rq + r;
        int cc = n0 + wn * 64 + in * 16 + col;
        out[(size_t)rr * 512 + cc] = acc[im][in][r];
      }
}

// ---------------------------------------------------------------------------
// K7: blocks [0,1024): x_c8 = x @ C8W^T (wave per 16 rows, shuffle reduce).
//     blocks [1024,1280): split-K reduce -> traj_c8.
// ---------------------------------------------------------------------------
__global__ __launch_bounds__(256) void k_xc8r(const void* x, const float* c8w,
                                              const float* Cp, void* dout,
                                              const int* flag) {
  int tid = threadIdx.x, lane = tid & 63, wid = tid >> 6;
  int isf = __builtin_amdgcn_readfirstlane(flag[0]);

  if (blockIdx.x >= 1024) {           // ---- split-K reduce ----
    int idx = (blockIdx.x - 1024) * 256 + tid;   // [0, 65536)
    const float4* c = (const float4*)Cp;
    float s0 = 0.f, s1 = 0.f, s2 = 0.f, s3 = 0.f;
#pragma unroll
    for (int p = 0; p < 8; p++) {
      float4 v = c[idx + p * 65536];
      s0 += v.x; s1 += v.y; s2 += v.z; s3 += v.w;
    }
    size_t base = 524288 + (size_t)idx * 4;
    if (isf) {
      float4 o; o.x = s0; o.y = s1; o.z = s2; o.w = s3;
      *(float4*)((float*)dout + base) = o;
    } else {
      unsigned int p0 = (unsigned int)f2bf(s0) | ((unsigned int)f2bf(s1) << 16);
      unsigned int p1 = (unsigned int)f2bf(s2) | ((unsigned int)f2bf(s3) << 16);
      uint2 pk; pk.x = p0; pk.y = p1;
      *(uint2*)((unsigned short*)dout + base) = pk;
    }
    return;
  }

  // ---- x_c8: wave per 16 rows, lane j covers col band, shuffle reduce ----
  int gw = blockIdx.x * 4 + wid;      // 4096 waves, 16 rows each
  float cw[8][8];
#pragma unroll
  for (int t = 0; t < 8; t++)
#pragma unroll
    for (int i = 0; i < 8; i++)
      cw[t][i] = c8w[i * 512 + t * 64 + lane];
  const float* xf = (const float*)x;
  const unsigned short* xh = (const unsigned short*)x;
  for (int r = gw * 16; r < gw * 16 + 16; r++) {
    float acc[8];
#pragma unroll
    for (int i = 0; i < 8; i++) acc[i] = 0.0f;
    if (isf) {
      const float* xr = xf + (size_t)r * 455;
#pragma unroll
      for (int t = 0; t < 8; t++) {
        int j = t * 64 + lane;
        float xv = (j < 455) ? xr[j] : 0.0f;
#pragma unroll
        for (int i = 0; i < 8; i++) acc[i] += xv * cw[t][i];
      }
    } else {
      const unsigned short* xr = xh + (size_t)r * 455;
#pragma unroll
      for (int t = 0; t < 8; t++) {
        int j = t * 64 + lane;
        float xv = (j < 455) ? bf2f(xr[j]) : 0.0f;
#pragma unroll
        for (int i = 0; i < 8; i++) acc[i] += xv * cw[t][i];
      }
    }
#pragma unroll
    for (int off = 32; off >= 1; off >>= 1)
#pragma unroll
      for (int i = 0; i < 8; i++) acc[i] += __shfl_xor(acc[i], off);
    float v = acc[0];
    v = (lane == 1) ? acc[1] : v;
    v = (lane == 2) ? acc[2] : v;
    v = (lane == 3) ? acc[3] : v;
    v = (lane == 4) ? acc[4] : v;
    v = (lane == 5) ? acc[5] : v;
    v = (lane == 6) ? acc[6] : v;
    v = (lane == 7) ? acc[7] : v;
    if (lane < 8) {
      if (isf) ((float*)dout)[(size_t)r * 8 + lane] = v;
      else     ((unsigned short*)dout)[(size_t)r * 8 + lane] = f2bf(v);
    }
  }
}

// ---------------------------------------------------------------------------
// host
// ---------------------------------------------------------------------------
extern "C" void kernel_launch(void* const* d_in, const int* in_sizes, int n_in,
                              void* d_out, int out_size, void* d_ws, size_t ws_size,
                              hipStream_t stream) {
  const void* x    = d_in[0];
  const void* traj = d_in[1];
  const void* w1l0 = d_in[2];
  const void* w1l1 = d_in[3];
  W2Ptrs w2;
  for (int l = 0; l < 7; l++) w2.p[l] = d_in[4 + l];

  char* ws = (char*)d_ws;
  double* exps          = (double*)(ws + 0);                 // 336*169*8
  float* dint           = (float*)(ws + 458752);             // 10*2048*4
  float* c8w            = (float*)(ws + 540672);             // 8*512*4
  unsigned short* dwt   = (unsigned short*)(ws + 573440);    // 512*2048*2
  float* feat           = (float*)(ws + 2670592);            // 512*160*4
  unsigned short* sig   = (unsigned short*)(ws + 2998272);   // 8192*2048*2
  unsigned short* f2    = (unsigned short*)(ws + 36552704);  // 8192*512*2
  unsigned short* et    = (unsigned short*)(ws + 44941312);  // 512*8192*2
  float* cp             = (float*)(ws + 53329920);           // 8*512*512*4
  int* flag             = (int*)(ws + 61718528);

  SetupArgs sa; QWArgs qa;
  for (int i = 0; i < 16; i++) sa.angA[i] = 2.0 * M_PI * (double)i / 16.0;
  static const double XB[8] = {
    -0.9602898564975363, -0.7966664774136267, -0.5255324099163290,
    -0.1834346424956498,  0.1834346424956498,  0.5255324099163290,
     0.7966664774136267,  0.9602898564975363};
  static const double WBv[8] = {
     0.1012285362903763, 0.2223810344533745, 0.3137066458778873,
     0.3626837833783620, 0.3626837833783620, 0.3137066458778873,
     0.2223810344533745, 0.1012285362903763};
  for (int i = 0; i < 8; i++) { sa.angB[i] = acos(XB[i]); qa.wb[i] = WBv[i]; }
  for (int i = 0; i < 8; i++) {
    double th = 2.0 * M_PI * (double)i / 8.0;
    double Mm[3][3] = {{cos(th), sin(th), 0.0},
                       {-sin(th), cos(th), 0.0},
                       {0.0, 0.0, 1.0}};
    double x0 = Mm[0][1], x1 = Mm[1][1], x2 = Mm[2][1];
    double bb = acos(fmax(-1.0, fmin(1.0, x1)));
    double aa = atan2(x0, x2);
    double ca_ = cos(aa), sa_ = sin(aa), cb_ = cos(bb), sb_ = sin(bb);
    double MY[3][3] = {{ca_, 0, sa_}, {0, 1, 0}, {-sa_, 0, ca_}};
    double MX[3][3] = {{1, 0, 0}, {0, cb_, -sb_}, {0, sb_, cb_}};
    double P1[3][3], Rr[3][3];
    for (int r = 0; r < 3; r++)
      for (int c = 0; c < 3; c++) {
        double s = 0.0;
        for (int k = 0; k < 3; k++) s += MY[r][k] * MX[k][c];
        P1[r][c] = s;
      }
    for (int r = 0; r < 3; r++)
      for (int c = 0; c < 3; c++) {
        double s = 0.0;
        for (int k = 0; k < 3; k++) s += P1[k][r] * Mm[k][c];  // P1^T @ M
        Rr[r][c] = s;
      }
    double gg = atan2(Rr[0][2], Rr[0][0]);
    sa.c8a[i] = aa; sa.c8b[i] = bb; sa.c8g[i] = gg;
  }

  k_exps<<<337, 192, 0, stream>>>(sa, exps, x, flag);
  k_assemble<<<4067, 192, 0, stream>>>(exps, qa, dwt, dint, c8w,
                                       traj, w1l0, w1l1, feat, flag);
  k_sig<<<4096, 256, 0, stream>>>(feat, dint, sig);
  k_ebuild<<<16384, 256, 0, stream>>>(w2, c8w, et, flag);
  k_gemm2<<<512, 256, 0, stream>>>(sig, dwt, f2);
  k_gemm3<<<256, 256, 0, stream>>>(f2, et, cp);
  k_xc8r<<<1280, 256, 0, stream>>>(x, c8w, cp, d_out, flag);
}

// Round 2
// 328.168 us; speedup vs baseline: 1.1645x; 1.0157x over previous
//
#include <hip/hip_runtime.h>
#include <hip/hip_bf16.h>
#include <math.h>

// ============================================================================
// EquiGroupSamplingC8 (f32 I/O confirmed by runtime sniff; bf16 path retained).
// R6: K1/K2 DP Wigner setup on fixed 13x13 padded matrices (unrolled).
// R7: K4 rebuilt (no scratch-indexed w2 ptrs, no global-table walk, magic div;
//     4 elems/thread). K5/K6 double-buffered 2-phase pipelines with raw
//     s_waitcnt+s_barrier and XCD-clustered block decode. K7: 8 rows/wave
//     (2x waves) + 27-shuffle reduce.
// ============================================================================

typedef __attribute__((ext_vector_type(8))) short bf16x8;
typedef __attribute__((ext_vector_type(4))) float f32x4;
typedef __attribute__((ext_vector_type(16))) float f32x16;

__device__ const int c_offs[8] = {0, 1, 10, 35, 84, 165, 286, 455};

struct SetupArgs {
  double angA[16];              // 2*pi*k/16 (alpha and gamma grid)
  double angB[8];               // arccos(GL8 nodes)
  double c8a[8], c8b[8], c8g[8];
};
struct QWArgs { double wb[8]; };
struct W2Ptrs { const void* p[7]; };

__device__ __forceinline__ float bf2f(unsigned short u) {
  union { unsigned int i; float f; } v; v.i = ((unsigned int)u) << 16; return v.f;
}
__device__ __forceinline__ unsigned short f2bf(float f) {
  union { float f; unsigned int i; } v; v.f = f;
  unsigned int r = v.i + 0x7fffu + ((v.i >> 16) & 1u);
  return (unsigned short)(r >> 16);
}
__device__ __forceinline__ float in_val(const void* p, size_t i, int isf) {
  return isf ? ((const float*)p)[i] : bf2f(((const unsigned short*)p)[i]);
}
__device__ __forceinline__ void gl_lds16(const void* g, void* lds) {
  __builtin_amdgcn_global_load_lds(
      (const __attribute__((address_space(1))) unsigned int*)g,
      (__attribute__((address_space(3))) unsigned int*)lds, 16, 0, 0);
}
__device__ __forceinline__ void wait_bar() {
  asm volatile("s_waitcnt vmcnt(0)\n\ts_barrier" ::: "memory");
}

// ---------------------------------------------------------------------------
// K1: exp matrices, fixed 13x13 padded. blocks [0,336) = 7 l * 48 items;
// block 336 = dtype sniff. 192 threads, 1 element/thread, all loops unrolled.
// ---------------------------------------------------------------------------
__global__ __launch_bounds__(192) void k_exps(SetupArgs args, double* exps,
                                              const void* x, int* flag) {
  __shared__ double Qr[169], Qi[169], Bm[169], R[169];
  __shared__ double coefA[13], coefB[13], rowsum[13];
  __shared__ double snorm;
  __shared__ int cnt;
  int tid = threadIdx.x;

  if (blockIdx.x == 336) {           // dtype sniff: f32 N(0,1) magnitude band
    if (tid == 0) cnt = 0;
    __syncthreads();
    if (tid < 64) {
      float v = ((const float*)x)[tid];
      float a = fabsf(v);
      int ok = (v == v) && (a > 9.0949470e-13f) && (a < 1.0995116e12f);
      atomicAdd(&cnt, ok);
    }
    __syncthreads();
    if (tid == 0) *flag = (cnt >= 32) ? 1 : 0;
    return;
  }

  int l = blockIdx.x / 48, item = blockIdx.x % 48;
  int e = tid;
  bool val = (e < 169);
  int r = e / 13, c = e % 13;

  if (val) { Qr[e] = 0.0; Qi[e] = 0.0; }
  __syncthreads();
  if (tid == 0) {
    const double is2 = 0.70710678118654752440;
    for (int m = -l; m <= l; m++) {
      int rr = l + m;
      if (m < 0) {
        Qr[rr * 13 + (l - m)] = is2;
        Qi[rr * 13 + (l + m)] = -is2;
      } else if (m == 0) {
        Qr[l * 13 + l] = 1.0;
      } else {
        double s = (m & 1) ? -1.0 : 1.0;
        Qr[rr * 13 + (l + m)] = s * is2;
        Qi[rr * 13 + (l - m)] = s * is2;
      }
    }
  }
  double jj = (double)l;
  if (tid < 13) {  // hoisted ladder coefficients (clamped: padded rows are *0)
    double m1 = (double)(tid - 1 - l);
    coefA[tid] = -0.5 * sqrt(fmax(jj * (jj + 1.0) - m1 * (m1 + 1.0), 0.0));
    double m2 = (double)(tid + 1 - l);
    coefB[tid] = 0.5 * sqrt(fmax(jj * (jj + 1.0) - m2 * (m2 - 1.0), 0.0));
  }
  __syncthreads();
  { // multiply by (-1j)^l
    int lm = l & 3;
    double pr = (lm == 0) ? 1.0 : (lm == 2 ? -1.0 : 0.0);
    double pi = (lm == 1) ? -1.0 : (lm == 3 ? 1.0 : 0.0);
    if (val) {
      double qr = Qr[e], qi = Qi[e];
      Qr[e] = qr * pr - qi * pi;
      Qi[e] = qr * pi + qi * pr;
    }
  }
  __syncthreads();

  double t; int axis;
  if (item < 16)      { t = args.angA[item];      axis = 1; }
  else if (item < 24) { t = args.angB[item - 16]; axis = 0; }
  else if (item < 32) { t = args.c8a[item - 24];  axis = 1; }
  else if (item < 40) { t = args.c8b[item - 32];  axis = 0; }
  else                { t = args.c8g[item - 40];  axis = 1; }

  if (val) {
    double accr = 0.0;
    if (axis == 1) {
#pragma unroll
      for (int p = 0; p < 13; p++) {
        double mp = (double)(p - l);
        double ar = Qr[p * 13 + r], ai = -Qi[p * 13 + r];
        double br = Qr[p * 13 + c], bi = Qi[p * 13 + c];
        accr += -mp * (ar * bi + ai * br);
      }
    } else {
#pragma unroll
      for (int p = 0; p < 13; p++) {
        double xr = 0.0, xi = 0.0;
        if (p > 0) {
          double v = coefA[p];
          xr += v * Qr[(p - 1) * 13 + c]; xi += v * Qi[(p - 1) * 13 + c];
        }
        if (p < 12) {
          double v = coefB[p];
          xr += v * Qr[(p + 1) * 13 + c]; xi += v * Qi[(p + 1) * 13 + c];
        }
        double ar = Qr[p * 13 + r], ai = -Qi[p * 13 + r];
        accr += ar * xr - ai * xi;
      }
    }
    Bm[e] = t * accr;
  }
  __syncthreads();
  if (tid < 13) {  // parallel row-sums for the scaling norm
    double s = 0.0;
#pragma unroll
    for (int cc = 0; cc < 13; cc++) s += fabs(Bm[tid * 13 + cc]);
    rowsum[tid] = s;
  }
  __syncthreads();
  if (tid == 0) {
    double mx = 0.0;
#pragma unroll
    for (int rr = 0; rr < 13; rr++) mx = fmax(mx, rowsum[rr]);
    int s = 0;
    while (mx > 0.5 && s < 48) { mx *= 0.5; s++; }
    snorm = (double)s;
  }
  __syncthreads();
  int sq = (int)snorm;
  double sc = 1.0;
  for (int i = 0; i < sq; i++) sc *= 0.5;
  if (val) {
    double b = Bm[e] * sc;
    Bm[e] = b;
    R[e] = b / 16.0 + ((r == c) ? 1.0 : 0.0);
  }
  __syncthreads();
  for (int k = 15; k >= 1; k--) {   // Horner: R <- Bm*R/k + I
    double acc = 0.0;
    if (val) {
#pragma unroll
      for (int p = 0; p < 13; p++) acc += Bm[r * 13 + p] * R[p * 13 + c];
    }
    __syncthreads();
    if (val) R[e] = acc / (double)k + ((r == c) ? 1.0 : 0.0);
    __syncthreads();
  }
  for (int i = 0; i < sq; i++) {    // squarings
    double acc = 0.0;
    if (val) {
#pragma unroll
      for (int p = 0; p < 13; p++) acc += R[r * 13 + p] * R[p * 13 + c];
    }
    __syncthreads();
    if (val) R[e] = acc;
    __syncthreads();
  }
  double* out = exps + (size_t)blockIdx.x * 169;
  if (val) out[e] = R[e];
}

// ---------------------------------------------------------------------------
// K2: assemble (192 threads, fixed 13x13). blocks [0,3584) = (l,a,b,cgrp)
// each 4 gammas: dwt/dint; [3584,3640) = (l,ci) c8 -> c8w f32;
// [3640,4067) = feat (proj_1).
// ---------------------------------------------------------------------------
__global__ __launch_bounds__(192) void k_assemble(const double* exps, QWArgs qw,
                                                  unsigned short* dwt, float* dint,
                                                  float* c8w,
                                                  const void* traj, const void* w1l0,
                                                  const void* w1l1, float* feat,
                                                  const int* flag) {
  __shared__ double Ea[169], Eb[169], Ec[169], T1[169];
  int tid = threadIdx.x;
  int bx = blockIdx.x;

  if (bx >= 3640) {                   // ---- feat (proj_1) ----
    int isf = __builtin_amdgcn_readfirstlane(flag[0]);
    int idx = (bx - 3640) * 192 + tid;
    if (idx >= 512 * 160) return;
    int bt = idx / 160, rem = idx % 160;
    int c = rem / 10, i = rem % 10;
    float v;
    if (i == 0) {
      v = in_val(traj, bt * 10 + 9, isf) * in_val(w1l0, c, isf);
    } else {
      int ii = i - 1, w = ii / 3, m = ii % 3;
      float acc = 0.0f;
      for (int u = 0; u < 3; u++)
        acc += in_val(traj, bt * 10 + 3 * u + m, isf) *
               in_val(w1l1, c * 9 + u * 3 + w, isf);
      v = acc * 0.57735026918962576f;
    }
    feat[idx] = v;
    return;
  }

  int e = tid;
  bool valp = (e < 169);
  int r = e / 13, c = e % 13;

  if (bx >= 3584) {                   // ---- C8 points ----
    int idx = bx - 3584;
    int l = idx / 8, ci = idx % 8;
    int d = 2 * l + 1;
    const double* pa = exps + (size_t)(l * 48 + 24 + ci) * 169;
    const double* pb = exps + (size_t)(l * 48 + 32 + ci) * 169;
    const double* pc = exps + (size_t)(l * 48 + 40 + ci) * 169;
    if (valp) { Ea[e] = pa[e]; Eb[e] = pb[e]; Ec[e] = pc[e]; }
    __syncthreads();
    if (valp) {
      double acc = 0.0;
#pragma unroll
      for (int p = 0; p < 13; p++) acc += Ea[r * 13 + p] * Eb[p * 13 + c];
      T1[e] = acc;
    }
    __syncthreads();
    double scale = sqrt((double)(2 * l + 1));
    if (valp) {
      double acc = 0.0;
#pragma unroll
      for (int p = 0; p < 13; p++) acc += T1[r * 13 + p] * Ec[p * 13 + c];
      if (r < d && c < d)
        c8w[ci * 512 + c_offs[l] + r * d + c] = (float)(scale * acc);
    }
    if (l == 0) {
      for (int jz = 455 + tid; jz < 512; jz += 192)
        c8w[ci * 512 + jz] = 0.0f;
    }
    return;
  }

  // ---- grid (l, a, b, cgrp), loop 4 gammas ----
  int l = bx / 512, rem = bx % 512;
  int a = rem >> 5, b = (rem >> 2) & 7, cg = rem & 3;
  int d = 2 * l + 1;
  const double* pa = exps + (size_t)(l * 48 + a) * 169;
  const double* pb = exps + (size_t)(l * 48 + 16 + b) * 169;
  if (valp) { Ea[e] = pa[e]; Eb[e] = pb[e]; }
  __syncthreads();
  if (valp) {
    double acc = 0.0;
#pragma unroll
    for (int p = 0; p < 13; p++) acc += Ea[r * 13 + p] * Eb[p * 13 + c];
    T1[e] = acc;
  }
  double scale = sqrt((double)(2 * l + 1));
  double qwv = qw.wb[b] * (1.0 / 512.0);
  bool inblk = valp && (r < d) && (c < d);
  int j = inblk ? (c_offs[l] + r * d + c) : 0;
  const double* ctab = exps + (size_t)(l * 48) * 169;   // items [0,16) = gamma
  for (int cc = cg * 4; cc < cg * 4 + 4; cc++) {
    __syncthreads();
    if (valp) Ec[e] = ctab[(size_t)cc * 169 + e];
    __syncthreads();
    int g = a * 128 + b * 16 + cc;
    if (valp) {
      double acc = 0.0;
#pragma unroll
      for (int p = 0; p < 13; p++) acc += T1[r * 13 + p] * Ec[p * 13 + c];
      if (inblk) {
        dwt[(size_t)j * 2048 + g] = f2bf((float)(scale * acc * qwv));
        if (l == 1) dint[(size_t)(1 + r * 3 + c) * 2048 + g] = (float)(scale * acc);
        if (l == 0 && e == 0) dint[g] = (float)(scale * acc);
      }
    }
    if (l == 0) {
      for (int jz = 455 + tid; jz < 512; jz += 192)
        dwt[(size_t)jz * 2048 + g] = 0;
    }
  }
}

// ---------------------------------------------------------------------------
// K3: sig [8192][2048] bf16 = relu(feat @ D_IN^T) * sqrt(2)
// ---------------------------------------------------------------------------
__global__ __launch_bounds__(256) void k_sig(const float* feat, const float* dint,
                                             unsigned short* sig) {
  int bi = blockIdx.x >> 3;
  int g = ((blockIdx.x & 7) << 8) + threadIdx.x;
  float din[10];
#pragma unroll
  for (int i = 0; i < 10; i++) din[i] = dint[(size_t)i * 2048 + g];
  const float* fr = feat + bi * 160;
  for (int cc = 0; cc < 16; cc++) {
    float acc = 0.0f;
#pragma unroll
    for (int i = 0; i < 10; i++) acc += fr[cc * 10 + i] * din[i];
    acc = fmaxf(acc, 0.0f) * 1.41421356237309505f;
    sig[(size_t)(bi * 16 + cc) * 2048 + g] = f2bf(acc);
  }
}

// ---------------------------------------------------------------------------
// K4: E_T [512][8192] bf16. 4 elems/thread, grid 4096. No runtime-indexed
// local arrays (w2 ptr via cndmask chain), l/offs/magic via compare chains,
// u = rloc/d via magic mul. ushort4 store.
// ---------------------------------------------------------------------------
__global__ __launch_bounds__(256) void k_ebuild(W2Ptrs w2, const float* c8w,
                                                unsigned short* et, const int* flag) {
  int isf = __builtin_amdgcn_readfirstlane(flag[0]);
  int base = (blockIdx.x * 256 + threadIdx.x) * 4;   // 512*16*512 total elems
  int n = base >> 13;
  int rest = base & 8191;
  int f = rest >> 9, jj0 = rest & 511;
  int g = n >> 3, i = n & 7;
  unsigned short ov[4];
#pragma unroll
  for (int s = 0; s < 4; s++) {
    int jj = jj0 + s;
    if (jj >= 455) { ov[s] = 0; continue; }
    int l    = (jj >= 1) + (jj >= 10) + (jj >= 35) + (jj >= 84) +
               (jj >= 165) + (jj >= 286);
    int offs = jj >= 286 ? 286 : jj >= 165 ? 165 : jj >= 84 ? 84 :
               jj >= 35 ? 35 : jj >= 10 ? 10 : jj >= 1 ? 1 : 0;
    int mg   = jj >= 286 ? 20165 : jj >= 165 ? 23832 : jj >= 84 ? 29128 :
               jj >= 35 ? 37450 : jj >= 10 ? 52429 : jj >= 1 ? 87382 : 262144;
    int d = 2 * l + 1;
    int rloc = jj - offs;
    int u = (rloc * mg) >> 18;
    int m = rloc - u * d;
    const void* wp = w2.p[0];
    wp = (l >= 1) ? w2.p[1] : wp;
    wp = (l >= 2) ? w2.p[2] : wp;
    wp = (l >= 3) ? w2.p[3] : wp;
    wp = (l >= 4) ? w2.p[4] : wp;
    wp = (l >= 5) ? w2.p[5] : wp;
    wp = (l >= 6) ? w2.p[6] : wp;
    float acc = 0.0f;
    for (int w = 0; w < d; w++) {
      float wv = in_val(wp, ((size_t)(f * 64 + g) * d + u) * d + w, isf);
      acc += wv * c8w[i * 512 + offs + w * d + m];
    }
    acc *= rsqrtf((float)(16 * d));
    ov[s] = f2bf(acc);
  }
  *(ushort4*)&et[(size_t)n * 8192 + f * 512 + jj0] =
      make_ushort4(ov[0], ov[1], ov[2], ov[3]);
}

// ---------------------------------------------------------------------------
// K5: GEMM2: f2[8192][512] = sig[8192][2048] @ dwt^T.
// BM=128 BN=64 BK=64, 32x32x16 MFMA, XOR-swizzled LDS, double-buffered
// 2-phase pipeline (stage next || compute cur; one raw vmcnt(0)+barrier per
// K-step). XCD-clustered decode: same-XCD blocks share the A band.
// ---------------------------------------------------------------------------
__global__ __launch_bounds__(256) void k_gemm2(const unsigned short* A,
                                               const unsigned short* B,
                                               unsigned short* C) {
  __shared__ __align__(16) unsigned short As[2][128 * 64];
  __shared__ __align__(16) unsigned short Bs[2][64 * 64];
  int tid = threadIdx.x;
  int lane = tid & 63, wid = tid >> 6;
  // XCD clustering: xcd = bid&7; 8 consecutive mt per XCD.
  int xcd = blockIdx.x & 7, bi = blockIdx.x >> 3;
  int mt = xcd * 8 + (bi >> 3), nt = bi & 7;
  int m0 = mt * 128, n0 = nt * 64;
  int wm = wid >> 1, wn = wid & 1;
  f32x16 acc[2];
#pragma unroll
  for (int t = 0; t < 2; t++)
#pragma unroll
    for (int r = 0; r < 16; r++) acc[t][r] = 0.0f;

  int r0 = tid >> 3;
  int kcl = (tid & 7) ^ (r0 & 7);          // logical k-chunk this lane fetches
  const unsigned short* Abase = A + (size_t)m0 * 2048;
  const unsigned short* Bbase = B + (size_t)n0 * 2048;
  int mrow = (lane & 31);
  int xr = lane & 7;
  int khalf = lane >> 5;

  auto STAGE = [&](int buf, int kt) {
    int k0 = kt * 64;
#pragma unroll
    for (int i = 0; i < 4; i++)
      gl_lds16(Abase + (size_t)(i * 32 + r0) * 2048 + k0 + kcl * 8,
               &As[buf][i * 2048 + wid * 512]);
#pragma unroll
    for (int i = 0; i < 2; i++)
      gl_lds16(Bbase + (size_t)(i * 32 + r0) * 2048 + k0 + kcl * 8,
               &Bs[buf][i * 2048 + wid * 512]);
  };

  STAGE(0, 0);
  wait_bar();
  int cur = 0;
  for (int kt = 0; kt < 32; kt++) {
    if (kt < 31) STAGE(cur ^ 1, kt + 1);
#pragma unroll
    for (int q = 0; q < 4; q++) {           // K quarters of 16
      int qc = q * 2 + khalf;               // logical k-chunk [0,8)
      bf16x8 bv = *(const bf16x8*)&Bs[cur][(wn * 32 + mrow) * 64 + (qc ^ xr) * 8];
#pragma unroll
      for (int t = 0; t < 2; t++) {
        bf16x8 av = *(const bf16x8*)&As[cur][(wm * 64 + t * 32 + mrow) * 64 + (qc ^ xr) * 8];
        acc[t] = __builtin_amdgcn_mfma_f32_32x32x16_bf16(av, bv, acc[t], 0, 0, 0);
      }
    }
    if (kt < 31) { wait_bar(); cur ^= 1; }
  }
  int col = n0 + wn * 32 + (lane & 31);
#pragma unroll
  for (int t = 0; t < 2; t++)
#pragma unroll
    for (int r = 0; r < 16; r++) {
      int row = m0 + wm * 64 + t * 32 + (r & 3) + 8 * (r >> 2) + 4 * (lane >> 5);
      C[(size_t)row * 512 + col] = f2bf(acc[t][r]);
    }
}

// ---------------------------------------------------------------------------
// K6: GEMM3 split-K=8: Cp[kc][512][512] f32 = f2[512][8192] @ E (E_T staged).
// Double-buffered 2-phase; decode mt=bid>>5, kc=(bid>>2)&7, nt=bid&3 so
// same-XCD blocks share B (et) slices in L2.
// ---------------------------------------------------------------------------
__global__ __launch_bounds__(256) void k_gemm3(const unsigned short* A,
                                               const unsigned short* B, float* Cp) {
  __shared__ __align__(16) unsigned short As[2][64 * 32];
  __shared__ __align__(16) unsigned short Bs[2][128 * 32];
  int tid = threadIdx.x, lane = tid & 63, wid = tid >> 6;
  int mt = blockIdx.x >> 5, kc = (blockIdx.x >> 2) & 7, nt = blockIdx.x & 3;
  int m0 = mt * 64, n0 = nt * 128;
  int wm = wid >> 1, wn = wid & 1;
  f32x4 acc[2][4];
#pragma unroll
  for (int a = 0; a < 2; a++)
#pragma unroll
    for (int b = 0; b < 4; b++) acc[a][b] = (f32x4){0.f, 0.f, 0.f, 0.f};
  int ar = tid >> 2, ak = (tid & 3) * 8;
  const unsigned short* Abase = A + (size_t)m0 * 8192 + kc * 1024;
  const unsigned short* Bbase = B + (size_t)n0 * 8192 + kc * 1024;
  int row = lane & 15, kq = (lane >> 4) * 8;

  auto STAGE = [&](int buf, int kt) {
    int k0 = kt * 32;
    gl_lds16(Abase + (size_t)ar * 8192 + k0 + ak, &As[buf][wid * 512]);
    gl_lds16(Bbase + (size_t)ar * 8192 + k0 + ak, &Bs[buf][wid * 512]);
    gl_lds16(Bbase + (size_t)(ar + 64) * 8192 + k0 + ak, &Bs[buf][2048 + wid * 512]);
  };

  STAGE(0, 0);
  wait_bar();
  int cur = 0;
  for (int kt = 0; kt < 32; kt++) {
    if (kt < 31) STAGE(cur ^ 1, kt + 1);
    bf16x8 af[2], bfr[4];
#pragma unroll
    for (int im = 0; im < 2; im++)
      af[im] = *(const bf16x8*)&As[cur][(wm * 32 + im * 16 + row) * 32 + kq];
#pragma unroll
    for (int in = 0; in < 4; in++)
      bfr[in] = *(const bf16x8*)&Bs[cur][(wn * 64 + in * 16 + row) * 32 + kq];
#pragma unroll
    for (int im = 0; im < 2; im++)
#pragma unroll
      for (int in = 0; in < 4; in++)
        acc[im][in] = __builtin_amdgcn_mfma_f32_16x16x32_bf16(af[im], bfr[in],
                                                              acc[im][in], 0, 0, 0);
    if (kt < 31) { wait_bar(); cur ^= 1; }
  }
  int col = lane & 15, rq = (lane >> 4) * 4;
  float* out = Cp + (size_t)kc * 262144;
#pragma unroll
  for (int im = 0; im < 2; im++)
#pragma unroll
    for (int in = 0; in < 4; in++)
#pragma unroll
      for (int r = 0; r < 4; r++) {
        int rr = m0 + wm * 32 + im * 16 + rq + r;
        int cc = n0 + wn * 64 + in * 16 + col;
        out[(size_t)rr * 512 + cc] = acc[im][in][r];
      }
}

// ---------------------------------------------------------------------------
// K7: blocks [0,2048): x_c8 = x @ C8W^T (wave per 8 rows, 27-shuffle reduce).
//     blocks [2048,2304): split-K reduce -> traj_c8.
// ---------------------------------------------------------------------------
__global__ __launch_bounds__(256) void k_xc8r(const void* x, const float* c8w,
                                              const float* Cp, void* dout,
                                              const int* flag) {
  int tid = threadIdx.x, lane = tid & 63, wid = tid >> 6;
  int isf = __builtin_amdgcn_readfirstlane(flag[0]);

  if (blockIdx.x >= 2048) {           // ---- split-K reduce ----
    int idx = (blockIdx.x - 2048) * 256 + tid;   // [0, 65536)
    const float4* c = (const float4*)Cp;
    float s0 = 0.f, s1 = 0.f, s2 = 0.f, s3 = 0.f;
#pragma unroll
    for (int p = 0; p < 8; p++) {
      float4 v = c[idx + p * 65536];
      s0 += v.x; s1 += v.y; s2 += v.z; s3 += v.w;
    }
    size_t base = 524288 + (size_t)idx * 4;
    if (isf) {
      float4 o; o.x = s0; o.y = s1; o.z = s2; o.w = s3;
      *(float4*)((float*)dout + base) = o;
    } else {
      unsigned int p0 = (unsigned int)f2bf(s0) | ((unsigned int)f2bf(s1) << 16);
      unsigned int p1 = (unsigned int)f2bf(s2) | ((unsigned int)f2bf(s3) << 16);
      uint2 pk; pk.x = p0; pk.y = p1;
      *(uint2*)((unsigned short*)dout + base) = pk;
    }
    return;
  }

  // ---- x_c8: wave per 8 rows, lane j covers col band ----
  int gw = blockIdx.x * 4 + wid;      // 8192 waves, 8 rows each
  float cw[8][8];
#pragma unroll
  for (int t = 0; t < 8; t++)
#pragma unroll
    for (int i = 0; i < 8; i++)
      cw[t][i] = c8w[i * 512 + t * 64 + lane];
  const float* xf = (const float*)x;
  const unsigned short* xh = (const unsigned short*)x;
  for (int r = gw * 8; r < gw * 8 + 8; r++) {
    float acc[8];
#pragma unroll
    for (int i = 0; i < 8; i++) acc[i] = 0.0f;
    if (isf) {
      const float* xr = xf + (size_t)r * 455;
#pragma unroll
      for (int t = 0; t < 8; t++) {
        int j = t * 64 + lane;
        float xv = (j < 455) ? xr[j] : 0.0f;
#pragma unroll
        for (int i = 0; i < 8; i++) acc[i] += xv * cw[t][i];
      }
    } else {
      const unsigned short* xr = xh + (size_t)r * 455;
#pragma unroll
      for (int t = 0; t < 8; t++) {
        int j = t * 64 + lane;
        float xv = (j < 455) ? bf2f(xr[j]) : 0.0f;
#pragma unroll
        for (int i = 0; i < 8; i++) acc[i] += xv * cw[t][i];
      }
    }
    // reduce within aligned 8-lane groups (offsets 1,2,4)
#pragma unroll
    for (int off = 1; off <= 4; off <<= 1)
#pragma unroll
      for (int i = 0; i < 8; i++) acc[i] += __shfl_xor(acc[i], off);
    // select acc[lane&7], then reduce across groups (offsets 8,16,32)
    int lg = lane & 7;
    float v = acc[0];
    v = (lg == 1) ? acc[1] : v;
    v = (lg == 2) ? acc[2] : v;
    v = (lg == 3) ? acc[3] : v;
    v = (lg == 4) ? acc[4] : v;
    v = (lg == 5) ? acc[5] : v;
    v = (lg == 6) ? acc[6] : v;
    v = (lg == 7) ? acc[7] : v;
    v += __shfl_xor(v, 8);
    v += __shfl_xor(v, 16);
    v += __shfl_xor(v, 32);
    if (lane < 8) {
      if (isf) ((float*)dout)[(size_t)r * 8 + lane] = v;
      else     ((unsigned short*)dout)[(size_t)r * 8 + lane] = f2bf(v);
    }
  }
}

// ---------------------------------------------------------------------------
// host
// ---------------------------------------------------------------------------
extern "C" void kernel_launch(void* const* d_in, const int* in_sizes, int n_in,
                              void* d_out, int out_size, void* d_ws, size_t ws_size,
                              hipStream_t stream) {
  const void* x    = d_in[0];
  const void* traj = d_in[1];
  const void* w1l0 = d_in[2];
  const void* w1l1 = d_in[3];
  W2Ptrs w2;
  for (int l = 0; l < 7; l++) w2.p[l] = d_in[4 + l];

  char* ws = (char*)d_ws;
  double* exps          = (double*)(ws + 0);                 // 336*169*8
  float* dint           = (float*)(ws + 458752);             // 10*2048*4
  float* c8w            = (float*)(ws + 540672);             // 8*512*4
  unsigned short* dwt   = (unsigned short*)(ws + 573440);    // 512*2048*2
  float* feat           = (float*)(ws + 2670592);            // 512*160*4
  unsigned short* sig   = (unsigned short*)(ws + 2998272);   // 8192*2048*2
  unsigned short* f2    = (unsigned short*)(ws + 36552704);  // 8192*512*2
  unsigned short* et    = (unsigned short*)(ws + 44941312);  // 512*8192*2
  float* cp             = (float*)(ws + 53329920);           // 8*512*512*4
  int* flag             = (int*)(ws + 61718528);

  SetupArgs sa; QWArgs qa;
  for (int i = 0; i < 16; i++) sa.angA[i] = 2.0 * M_PI * (double)i / 16.0;
  static const double XB[8] = {
    -0.9602898564975363, -0.7966664774136267, -0.5255324099163290,
    -0.1834346424956498,  0.1834346424956498,  0.5255324099163290,
     0.7966664774136267,  0.9602898564975363};
  static const double WBv[8] = {
     0.1012285362903763, 0.2223810344533745, 0.3137066458778873,
     0.3626837833783620, 0.3626837833783620, 0.3137066458778873,
     0.2223810344533745, 0.1012285362903763};
  for (int i = 0; i < 8; i++) { sa.angB[i] = acos(XB[i]); qa.wb[i] = WBv[i]; }
  for (int i = 0; i < 8; i++) {
    double th = 2.0 * M_PI * (double)i / 8.0;
    double Mm[3][3] = {{cos(th), sin(th), 0.0},
                       {-sin(th), cos(th), 0.0},
                       {0.0, 0.0, 1.0}};
    double x0 = Mm[0][1], x1 = Mm[1][1], x2 = Mm[2][1];
    double bb = acos(fmax(-1.0, fmin(1.0, x1)));
    double aa = atan2(x0, x2);
    double ca_ = cos(aa), sa_ = sin(aa), cb_ = cos(bb), sb_ = sin(bb);
    double MY[3][3] = {{ca_, 0, sa_}, {0, 1, 0}, {-sa_, 0, ca_}};
    double MX[3][3] = {{1, 0, 0}, {0, cb_, -sb_}, {0, sb_, cb_}};
    double P1[3][3], Rr[3][3];
    for (int r = 0; r < 3; r++)
      for (int c = 0; c < 3; c++) {
        double s = 0.0;
        for (int k = 0; k < 3; k++) s += MY[r][k] * MX[k][c];
        P1[r][c] = s;
      }
    for (int r = 0; r < 3; r++)
      for (int c = 0; c < 3; c++) {
        double s = 0.0;
        for (int k = 0; k < 3; k++) s += P1[k][r] * Mm[k][c];  // P1^T @ M
        Rr[r][c] = s;
      }
    double gg = atan2(Rr[0][2], Rr[0][0]);
    sa.c8a[i] = aa; sa.c8b[i] = bb; sa.c8g[i] = gg;
  }

  k_exps<<<337, 192, 0, stream>>>(sa, exps, x, flag);
  k_assemble<<<4067, 192, 0, stream>>>(exps, qa, dwt, dint, c8w,
                                       traj, w1l0, w1l1, feat, flag);
  k_sig<<<4096, 256, 0, stream>>>(feat, dint, sig);
  k_ebuild<<<4096, 256, 0, stream>>>(w2, c8w, et, flag);
  k_gemm2<<<512, 256, 0, stream>>>(sig, dwt, f2);
  k_gemm3<<<256, 256, 0, stream>>>(f2, et, cp);
  k_xc8r<<<2304, 256, 0, stream>>>(x, c8w, cp, d_out, flag);
}

// Round 3
// 327.823 us; speedup vs baseline: 1.1657x; 1.0010x over previous
//
#include <hip/hip_runtime.h>
#include <hip/hip_bf16.h>
#include <math.h>

// ============================================================================
// EquiGroupSamplingC8 (f32 I/O confirmed by runtime sniff; bf16 path retained).
// R6: K1/K2 DP Wigner setup on fixed 13x13 padded matrices (unrolled).
// R8: K5/K6 3-buffer counted-vmcnt pipelines (T4: never drain vmcnt to 0 in
//     the K-loop; 1 barrier/step). K6 retiled 64x64, grid 512. K2 main
//     section does 16 gammas/block with register-buffered uint4 stores.
//     K3+K4 fused into k_post (6 launches total).
// ============================================================================

typedef __attribute__((ext_vector_type(8))) short bf16x8;
typedef __attribute__((ext_vector_type(4))) float f32x4;
typedef __attribute__((ext_vector_type(16))) float f32x16;

__device__ const int c_offs[8] = {0, 1, 10, 35, 84, 165, 286, 455};

struct SetupArgs {
  double angA[16];              // 2*pi*k/16 (alpha and gamma grid)
  double angB[8];               // arccos(GL8 nodes)
  double c8a[8], c8b[8], c8g[8];
};
struct QWArgs { double wb[8]; };
struct W2Ptrs { const void* p[7]; };

__device__ __forceinline__ float bf2f(unsigned short u) {
  union { unsigned int i; float f; } v; v.i = ((unsigned int)u) << 16; return v.f;
}
__device__ __forceinline__ unsigned short f2bf(float f) {
  union { float f; unsigned int i; } v; v.f = f;
  unsigned int r = v.i + 0x7fffu + ((v.i >> 16) & 1u);
  return (unsigned short)(r >> 16);
}
__device__ __forceinline__ float in_val(const void* p, size_t i, int isf) {
  return isf ? ((const float*)p)[i] : bf2f(((const unsigned short*)p)[i]);
}
__device__ __forceinline__ void gl_lds16(const void* g, void* lds) {
  __builtin_amdgcn_global_load_lds(
      (const __attribute__((address_space(1))) unsigned int*)g,
      (__attribute__((address_space(3))) unsigned int*)lds, 16, 0, 0);
}

// ---------------------------------------------------------------------------
// K1: exp matrices, fixed 13x13 padded. blocks [0,336) = 7 l * 48 items;
// block 336 = dtype sniff. 192 threads, 1 element/thread, all loops unrolled.
// ---------------------------------------------------------------------------
__global__ __launch_bounds__(192) void k_exps(SetupArgs args, double* exps,
                                              const void* x, int* flag) {
  __shared__ double Qr[169], Qi[169], Bm[169], R[169];
  __shared__ double coefA[13], coefB[13], rowsum[13];
  __shared__ double snorm;
  __shared__ int cnt;
  int tid = threadIdx.x;

  if (blockIdx.x == 336) {           // dtype sniff: f32 N(0,1) magnitude band
    if (tid == 0) cnt = 0;
    __syncthreads();
    if (tid < 64) {
      float v = ((const float*)x)[tid];
      float a = fabsf(v);
      int ok = (v == v) && (a > 9.0949470e-13f) && (a < 1.0995116e12f);
      atomicAdd(&cnt, ok);
    }
    __syncthreads();
    if (tid == 0) *flag = (cnt >= 32) ? 1 : 0;
    return;
  }

  int l = blockIdx.x / 48, item = blockIdx.x % 48;
  int e = tid;
  bool val = (e < 169);
  int r = e / 13, c = e % 13;

  if (val) { Qr[e] = 0.0; Qi[e] = 0.0; }
  __syncthreads();
  if (tid == 0) {
    const double is2 = 0.70710678118654752440;
    for (int m = -l; m <= l; m++) {
      int rr = l + m;
      if (m < 0) {
        Qr[rr * 13 + (l - m)] = is2;
        Qi[rr * 13 + (l + m)] = -is2;
      } else if (m == 0) {
        Qr[l * 13 + l] = 1.0;
      } else {
        double s = (m & 1) ? -1.0 : 1.0;
        Qr[rr * 13 + (l + m)] = s * is2;
        Qi[rr * 13 + (l - m)] = s * is2;
      }
    }
  }
  double jj = (double)l;
  if (tid < 13) {  // hoisted ladder coefficients (clamped: padded rows are *0)
    double m1 = (double)(tid - 1 - l);
    coefA[tid] = -0.5 * sqrt(fmax(jj * (jj + 1.0) - m1 * (m1 + 1.0), 0.0));
    double m2 = (double)(tid + 1 - l);
    coefB[tid] = 0.5 * sqrt(fmax(jj * (jj + 1.0) - m2 * (m2 - 1.0), 0.0));
  }
  __syncthreads();
  { // multiply by (-1j)^l
    int lm = l & 3;
    double pr = (lm == 0) ? 1.0 : (lm == 2 ? -1.0 : 0.0);
    double pi = (lm == 1) ? -1.0 : (lm == 3 ? 1.0 : 0.0);
    if (val) {
      double qr = Qr[e], qi = Qi[e];
      Qr[e] = qr * pr - qi * pi;
      Qi[e] = qr * pi + qi * pr;
    }
  }
  __syncthreads();

  double t; int axis;
  if (item < 16)      { t = args.angA[item];      axis = 1; }
  else if (item < 24) { t = args.angB[item - 16]; axis = 0; }
  else if (item < 32) { t = args.c8a[item - 24];  axis = 1; }
  else if (item < 40) { t = args.c8b[item - 32];  axis = 0; }
  else                { t = args.c8g[item - 40];  axis = 1; }

  if (val) {
    double accr = 0.0;
    if (axis == 1) {
#pragma unroll
      for (int p = 0; p < 13; p++) {
        double mp = (double)(p - l);
        double ar = Qr[p * 13 + r], ai = -Qi[p * 13 + r];
        double br = Qr[p * 13 + c], bi = Qi[p * 13 + c];
        accr += -mp * (ar * bi + ai * br);
      }
    } else {
#pragma unroll
      for (int p = 0; p < 13; p++) {
        double xr = 0.0, xi = 0.0;
        if (p > 0) {
          double v = coefA[p];
          xr += v * Qr[(p - 1) * 13 + c]; xi += v * Qi[(p - 1) * 13 + c];
        }
        if (p < 12) {
          double v = coefB[p];
          xr += v * Qr[(p + 1) * 13 + c]; xi += v * Qi[(p + 1) * 13 + c];
        }
        double ar = Qr[p * 13 + r], ai = -Qi[p * 13 + r];
        accr += ar * xr - ai * xi;
      }
    }
    Bm[e] = t * accr;
  }
  __syncthreads();
  if (tid < 13) {  // parallel row-sums for the scaling norm
    double s = 0.0;
#pragma unroll
    for (int cc = 0; cc < 13; cc++) s += fabs(Bm[tid * 13 + cc]);
    rowsum[tid] = s;
  }
  __syncthreads();
  if (tid == 0) {
    double mx = 0.0;
#pragma unroll
    for (int rr = 0; rr < 13; rr++) mx = fmax(mx, rowsum[rr]);
    int s = 0;
    while (mx > 0.5 && s < 48) { mx *= 0.5; s++; }
    snorm = (double)s;
  }
  __syncthreads();
  int sq = (int)snorm;
  double sc = 1.0;
  for (int i = 0; i < sq; i++) sc *= 0.5;
  if (val) {
    double b = Bm[e] * sc;
    Bm[e] = b;
    R[e] = b / 16.0 + ((r == c) ? 1.0 : 0.0);
  }
  __syncthreads();
  for (int k = 15; k >= 1; k--) {   // Horner: R <- Bm*R/k + I
    double acc = 0.0;
    if (val) {
#pragma unroll
      for (int p = 0; p < 13; p++) acc += Bm[r * 13 + p] * R[p * 13 + c];
    }
    __syncthreads();
    if (val) R[e] = acc / (double)k + ((r == c) ? 1.0 : 0.0);
    __syncthreads();
  }
  for (int i = 0; i < sq; i++) {    // squarings
    double acc = 0.0;
    if (val) {
#pragma unroll
      for (int p = 0; p < 13; p++) acc += R[r * 13 + p] * R[p * 13 + c];
    }
    __syncthreads();
    if (val) R[e] = acc;
    __syncthreads();
  }
  double* out = exps + (size_t)blockIdx.x * 169;
  if (val) out[e] = R[e];
}

// ---------------------------------------------------------------------------
// K2: assemble (192 threads, fixed 13x13).
// blocks [0,896) = (l,a,b), 16 gammas each, register-buffered uint4 stores;
// [896,952) = (l,ci) c8 -> c8w f32; [952,1379) = feat (proj_1).
// ---------------------------------------------------------------------------
__global__ __launch_bounds__(192) void k_assemble(const double* exps, QWArgs qw,
                                                  unsigned short* dwt, float* dint,
                                                  float* c8w,
                                                  const void* traj, const void* w1l0,
                                                  const void* w1l1, float* feat,
                                                  const int* flag) {
  __shared__ double Ea[169], Eb[169], Ec[169], T1[169];
  int tid = threadIdx.x;
  int bx = blockIdx.x;

  if (bx >= 952) {                    // ---- feat (proj_1) ----
    int isf = __builtin_amdgcn_readfirstlane(flag[0]);
    int idx = (bx - 952) * 192 + tid;
    if (idx >= 512 * 160) return;
    int bt = idx / 160, rem = idx % 160;
    int c = rem / 10, i = rem % 10;
    float v;
    if (i == 0) {
      v = in_val(traj, bt * 10 + 9, isf) * in_val(w1l0, c, isf);
    } else {
      int ii = i - 1, w = ii / 3, m = ii % 3;
      float acc = 0.0f;
      for (int u = 0; u < 3; u++)
        acc += in_val(traj, bt * 10 + 3 * u + m, isf) *
               in_val(w1l1, c * 9 + u * 3 + w, isf);
      v = acc * 0.57735026918962576f;
    }
    feat[idx] = v;
    return;
  }

  int e = tid;
  bool valp = (e < 169);
  int r = e / 13, c = e % 13;

  if (bx >= 896) {                    // ---- C8 points ----
    int idx = bx - 896;
    int l = idx / 8, ci = idx % 8;
    int d = 2 * l + 1;
    const double* pa = exps + (size_t)(l * 48 + 24 + ci) * 169;
    const double* pb = exps + (size_t)(l * 48 + 32 + ci) * 169;
    const double* pc = exps + (size_t)(l * 48 + 40 + ci) * 169;
    if (valp) { Ea[e] = pa[e]; Eb[e] = pb[e]; Ec[e] = pc[e]; }
    __syncthreads();
    if (valp) {
      double acc = 0.0;
#pragma unroll
      for (int p = 0; p < 13; p++) acc += Ea[r * 13 + p] * Eb[p * 13 + c];
      T1[e] = acc;
    }
    __syncthreads();
    double scale = sqrt((double)(2 * l + 1));
    if (valp) {
      double acc = 0.0;
#pragma unroll
      for (int p = 0; p < 13; p++) acc += T1[r * 13 + p] * Ec[p * 13 + c];
      if (r < d && c < d)
        c8w[ci * 512 + c_offs[l] + r * d + c] = (float)(scale * acc);
    }
    if (l == 0) {
      for (int jz = 455 + tid; jz < 512; jz += 192)
        c8w[ci * 512 + jz] = 0.0f;
    }
    return;
  }

  // ---- grid (l, a, b), all 16 gammas in-register ----
  int l = bx >> 7, rem = bx & 127;
  int a = rem >> 3, b = rem & 7;
  int d = 2 * l + 1;
  const double* pa = exps + (size_t)(l * 48 + a) * 169;
  const double* pb = exps + (size_t)(l * 48 + 16 + b) * 169;
  if (valp) { Ea[e] = pa[e]; Eb[e] = pb[e]; }
  __syncthreads();
  if (valp) {
    double acc = 0.0;
#pragma unroll
    for (int p = 0; p < 13; p++) acc += Ea[r * 13 + p] * Eb[p * 13 + c];
    T1[e] = acc;
  }
  double scale = sqrt((double)(2 * l + 1));
  double qwv = qw.wb[b] * (1.0 / 512.0);
  bool inblk = valp && (r < d) && (c < d);
  int j = inblk ? (c_offs[l] + r * d + c) : 0;
  int g0 = a * 128 + b * 16;
  const double* ctab = exps + (size_t)(l * 48) * 169;   // items [0,16) = gamma
  unsigned int ow[8];
  float dv[16];
#pragma unroll
  for (int cc = 0; cc < 16; cc++) {
    __syncthreads();
    if (valp) Ec[e] = ctab[(size_t)cc * 169 + e];
    __syncthreads();
    double acc = 0.0;
    if (valp) {
#pragma unroll
      for (int p = 0; p < 13; p++) acc += T1[r * 13 + p] * Ec[p * 13 + c];
    }
    unsigned int hv = (unsigned int)f2bf((float)(scale * acc * qwv));
    if ((cc & 1) == 0) ow[cc >> 1] = hv;
    else               ow[cc >> 1] |= hv << 16;
    dv[cc] = (float)(scale * acc);
  }
  if (inblk) {
    unsigned short* wp = &dwt[(size_t)j * 2048 + g0];
    *(uint4*)&wp[0] = make_uint4(ow[0], ow[1], ow[2], ow[3]);
    *(uint4*)&wp[8] = make_uint4(ow[4], ow[5], ow[6], ow[7]);
    if (l == 1) {
      float* dp = &dint[(size_t)(1 + r * 3 + c) * 2048 + g0];
      *(float4*)&dp[0]  = make_float4(dv[0],  dv[1],  dv[2],  dv[3]);
      *(float4*)&dp[4]  = make_float4(dv[4],  dv[5],  dv[6],  dv[7]);
      *(float4*)&dp[8]  = make_float4(dv[8],  dv[9],  dv[10], dv[11]);
      *(float4*)&dp[12] = make_float4(dv[12], dv[13], dv[14], dv[15]);
    }
    if (l == 0) {
      float* dp = &dint[g0];
      *(float4*)&dp[0]  = make_float4(dv[0],  dv[1],  dv[2],  dv[3]);
      *(float4*)&dp[4]  = make_float4(dv[4],  dv[5],  dv[6],  dv[7]);
      *(float4*)&dp[8]  = make_float4(dv[8],  dv[9],  dv[10], dv[11]);
      *(float4*)&dp[12] = make_float4(dv[12], dv[13], dv[14], dv[15]);
    }
  }
  if (l == 0 && tid < 57) {          // zero rows 455..511 for this g-band
    unsigned short* zp = &dwt[(size_t)(455 + tid) * 2048 + g0];
    *(uint4*)&zp[0] = make_uint4(0, 0, 0, 0);
    *(uint4*)&zp[8] = make_uint4(0, 0, 0, 0);
  }
}

// ---------------------------------------------------------------------------
// K3+K4 fused: blocks [0,4096) = sig; [4096,8192) = E_T build.
// ---------------------------------------------------------------------------
__global__ __launch_bounds__(256) void k_post(const float* feat, const float* dint,
                                              unsigned short* sig, W2Ptrs w2,
                                              const float* c8w, unsigned short* et,
                                              const int* flag) {
  int bx = blockIdx.x;
  if (bx < 4096) {                    // ---- sig = relu(feat @ D_IN^T)*sqrt2 ----
    int bi = bx >> 3;
    int g = ((bx & 7) << 8) + threadIdx.x;
    float din[10];
#pragma unroll
    for (int i = 0; i < 10; i++) din[i] = dint[(size_t)i * 2048 + g];
    const float* fr = feat + bi * 160;
    for (int cc = 0; cc < 16; cc++) {
      float acc = 0.0f;
#pragma unroll
      for (int i = 0; i < 10; i++) acc += fr[cc * 10 + i] * din[i];
      acc = fmaxf(acc, 0.0f) * 1.41421356237309505f;
      sig[(size_t)(bi * 16 + cc) * 2048 + g] = f2bf(acc);
    }
    return;
  }
  // ---- E_T [512][8192] bf16, 4 elems/thread ----
  int isf = __builtin_amdgcn_readfirstlane(flag[0]);
  int base = ((bx - 4096) * 256 + threadIdx.x) * 4;
  int n = base >> 13;
  int rest = base & 8191;
  int f = rest >> 9, jj0 = rest & 511;
  int g = n >> 3, i = n & 7;
  unsigned short ov[4];
#pragma unroll
  for (int s = 0; s < 4; s++) {
    int jj = jj0 + s;
    if (jj >= 455) { ov[s] = 0; continue; }
    int l    = (jj >= 1) + (jj >= 10) + (jj >= 35) + (jj >= 84) +
               (jj >= 165) + (jj >= 286);
    int offs = jj >= 286 ? 286 : jj >= 165 ? 165 : jj >= 84 ? 84 :
               jj >= 35 ? 35 : jj >= 10 ? 10 : jj >= 1 ? 1 : 0;
    int mg   = jj >= 286 ? 20165 : jj >= 165 ? 23832 : jj >= 84 ? 29128 :
               jj >= 35 ? 37450 : jj >= 10 ? 52429 : jj >= 1 ? 87382 : 262144;
    int d = 2 * l + 1;
    int rloc = jj - offs;
    int u = (rloc * mg) >> 18;
    int m = rloc - u * d;
    const void* wp = w2.p[0];
    wp = (l >= 1) ? w2.p[1] : wp;
    wp = (l >= 2) ? w2.p[2] : wp;
    wp = (l >= 3) ? w2.p[3] : wp;
    wp = (l >= 4) ? w2.p[4] : wp;
    wp = (l >= 5) ? w2.p[5] : wp;
    wp = (l >= 6) ? w2.p[6] : wp;
    float acc = 0.0f;
    for (int w = 0; w < d; w++) {
      float wv = in_val(wp, ((size_t)(f * 64 + g) * d + u) * d + w, isf);
      acc += wv * c8w[i * 512 + offs + w * d + m];
    }
    acc *= rsqrtf((float)(16 * d));
    ov[s] = f2bf(acc);
  }
  *(ushort4*)&et[(size_t)n * 8192 + f * 512 + jj0] =
      make_ushort4(ov[0], ov[1], ov[2], ov[3]);
}

// ---------------------------------------------------------------------------
// K5: GEMM2: f2[8192][512] = sig[8192][2048] @ dwt^T.
// BM=128 BN=64 BK=64, 32x32x16 MFMA, XOR-swizzled LDS, 3-buffer counted-vmcnt
// pipeline: stage kt+2 after compute kt; s_waitcnt vmcnt(6) (not 0) + one
// s_barrier per K-step, so 2 stages stay in flight across the barrier.
// ---------------------------------------------------------------------------
__global__ __launch_bounds__(256) void k_gemm2(const unsigned short* A,
                                               const unsigned short* B,
                                               unsigned short* C) {
  __shared__ __align__(16) unsigned short As[3][128 * 64];
  __shared__ __align__(16) unsigned short Bs[3][64 * 64];
  int tid = threadIdx.x;
  int lane = tid & 63, wid = tid >> 6;
  int xcd = blockIdx.x & 7, bi = blockIdx.x >> 3;
  int mt = xcd * 8 + (bi >> 3), nt = bi & 7;
  int m0 = mt * 128, n0 = nt * 64;
  int wm = wid >> 1, wn = wid & 1;
  f32x16 acc[2];
#pragma unroll
  for (int t = 0; t < 2; t++)
#pragma unroll
    for (int r = 0; r < 16; r++) acc[t][r] = 0.0f;

  int r0 = tid >> 3;
  int kcl = (tid & 7) ^ (r0 & 7);          // logical k-chunk this lane fetches
  const unsigned short* Abase = A + (size_t)m0 * 2048;
  const unsigned short* Bbase = B + (size_t)n0 * 2048;
  int mrow = (lane & 31);
  int xr = lane & 7;
  int khalf = lane >> 5;

  auto STAGE = [&](int buf, int kt) {
    int k0 = kt * 64;
#pragma unroll
    for (int i = 0; i < 4; i++)
      gl_lds16(Abase + (size_t)(i * 32 + r0) * 2048 + k0 + kcl * 8,
               &As[buf][i * 2048 + wid * 512]);
#pragma unroll
    for (int i = 0; i < 2; i++)
      gl_lds16(Bbase + (size_t)(i * 32 + r0) * 2048 + k0 + kcl * 8,
               &Bs[buf][i * 2048 + wid * 512]);
  };

  STAGE(0, 0);
  STAGE(1, 1);
  int cb = 0;
  for (int kt = 0; kt < 32; kt++) {
    if (kt < 31) asm volatile("s_waitcnt vmcnt(6)" ::: "memory");
    else         asm volatile("s_waitcnt vmcnt(0)" ::: "memory");
    __builtin_amdgcn_s_barrier();
    __builtin_amdgcn_sched_barrier(0);
    const unsigned short* Ab = As[cb];
    const unsigned short* Bb = Bs[cb];
#pragma unroll
    for (int q = 0; q < 4; q++) {           // K quarters of 16
      int qc = q * 2 + khalf;               // logical k-chunk [0,8)
      bf16x8 bv = *(const bf16x8*)&Bb[(wn * 32 + mrow) * 64 + (qc ^ xr) * 8];
#pragma unroll
      for (int t = 0; t < 2; t++) {
        bf16x8 av = *(const bf16x8*)&Ab[(wm * 64 + t * 32 + mrow) * 64 + (qc ^ xr) * 8];
        acc[t] = __builtin_amdgcn_mfma_f32_32x32x16_bf16(av, bv, acc[t], 0, 0, 0);
      }
    }
    if (kt < 30) STAGE(cb == 0 ? 2 : cb - 1, kt + 2);
    cb = (cb == 2) ? 0 : cb + 1;
  }
  int col = n0 + wn * 32 + (lane & 31);
#pragma unroll
  for (int t = 0; t < 2; t++)
#pragma unroll
    for (int r = 0; r < 16; r++) {
      int row = m0 + wm * 64 + t * 32 + (r & 3) + 8 * (r >> 2) + 4 * (lane >> 5);
      C[(size_t)row * 512 + col] = f2bf(acc[t][r]);
    }
}

// ---------------------------------------------------------------------------
// K6: GEMM3 split-K=8: Cp[kc][512][512] f32 = f2[512][8192] @ E (E_T staged).
// BM=64 BN=64 (grid 512, 2 blocks/CU), 3-buffer counted-vmcnt pipeline.
// ---------------------------------------------------------------------------
__global__ __launch_bounds__(256) void k_gemm3(const unsigned short* A,
                                               const unsigned short* B, float* Cp) {
  __shared__ __align__(16) unsigned short As[3][64 * 32];
  __shared__ __align__(16) unsigned short Bs[3][64 * 32];
  int tid = threadIdx.x, lane = tid & 63, wid = tid >> 6;
  int kc = blockIdx.x >> 6, mt = (blockIdx.x >> 3) & 7, nt = blockIdx.x & 7;
  int m0 = mt * 64, n0 = nt * 64;
  int wm = wid >> 1, wn = wid & 1;
  f32x4 acc[2][2];
#pragma unroll
  for (int a = 0; a < 2; a++)
#pragma unroll
    for (int b = 0; b < 2; b++) acc[a][b] = (f32x4){0.f, 0.f, 0.f, 0.f};
  int ar = tid >> 2, ak = (tid & 3) * 8;
  const unsigned short* Abase = A + (size_t)m0 * 8192 + kc * 1024;
  const unsigned short* Bbase = B + (size_t)n0 * 8192 + kc * 1024;
  int row = lane & 15, kq = (lane >> 4) * 8;

  auto STAGE = [&](int buf, int kt) {
    int k0 = kt * 32;
    gl_lds16(Abase + (size_t)ar * 8192 + k0 + ak, &As[buf][wid * 512]);
    gl_lds16(Bbase + (size_t)ar * 8192 + k0 + ak, &Bs[buf][wid * 512]);
  };

  STAGE(0, 0);
  STAGE(1, 1);
  int cb = 0;
  for (int kt = 0; kt < 32; kt++) {
    if (kt < 31) asm volatile("s_waitcnt vmcnt(2)" ::: "memory");
    else         asm volatile("s_waitcnt vmcnt(0)" ::: "memory");
    __builtin_amdgcn_s_barrier();
    __builtin_amdgcn_sched_barrier(0);
    bf16x8 af[2], bfr[2];
#pragma unroll
    for (int im = 0; im < 2; im++)
      af[im] = *(const bf16x8*)&As[cb][(wm * 32 + im * 16 + row) * 32 + kq];
#pragma unroll
    for (int in = 0; in < 2; in++)
      bfr[in] = *(const bf16x8*)&Bs[cb][(wn * 32 + in * 16 + row) * 32 + kq];
#pragma unroll
    for (int im = 0; im < 2; im++)
#pragma unroll
      for (int in = 0; in < 2; in++)
        acc[im][in] = __builtin_amdgcn_mfma_f32_16x16x32_bf16(af[im], bfr[in],
                                                              acc[im][in], 0, 0, 0);
    if (kt < 30) STAGE(cb == 0 ? 2 : cb - 1, kt + 2);
    cb = (cb == 2) ? 0 : cb + 1;
  }
  int col = lane & 15, rq = (lane >> 4) * 4;
  float* out = Cp + (size_t)kc * 262144;
#pragma unroll
  for (int im = 0; im < 2; im++)
#pragma unroll
    for (int in = 0; in < 2; in++)
#pragma unroll
      for (int r = 0; r < 4; r++) {
        int rr = m0 + wm * 32 + im * 16 + rq + r;
        int cc = n0 + wn * 32 + in * 16 + col;
        out[(size_t)rr * 512 + cc] = acc[im][in][r];
      }
}

// ---------------------------------------------------------------------------
// K7: blocks [0,2048): x_c8 = x @ C8W^T (wave per 8 rows, 27-shuffle reduce).
//     blocks [2048,2304): split-K reduce -> traj_c8.
// ---------------------------------------------------------------------------
__global__ __launch_bounds__(256) void k_xc8r(const void* x, const float* c8w,
                                              const float* Cp, void* dout,
                                              const int* flag) {
  int tid = threadIdx.x, lane = tid & 63, wid = tid >> 6;
  int isf = __builtin_amdgcn_readfirstlane(flag[0]);

  if (blockIdx.x >= 2048) {           // ---- split-K reduce ----
    int idx = (blockIdx.x - 2048) * 256 + tid;   // [0, 65536)
    const float4* c = (const float4*)Cp;
    float s0 = 0.f, s1 = 0.f, s2 = 0.f, s3 = 0.f;
#pragma unroll
    for (int p = 0; p < 8; p++) {
      float4 v = c[idx + p * 65536];
      s0 += v.x; s1 += v.y; s2 += v.z; s3 += v.w;
    }
    size_t base = 524288 + (size_t)idx * 4;
    if (isf) {
      float4 o; o.x = s0; o.y = s1; o.z = s2; o.w = s3;
      *(float4*)((float*)dout + base) = o;
    } else {
      unsigned int p0 = (unsigned int)f2bf(s0) | ((unsigned int)f2bf(s1) << 16);
      unsigned int p1 = (unsigned int)f2bf(s2) | ((unsigned int)f2bf(s3) << 16);
      uint2 pk; pk.x = p0; pk.y = p1;
      *(uint2*)((unsigned short*)dout + base) = pk;
    }
    return;
  }

  // ---- x_c8: wave per 8 rows, lane j covers col band ----
  int gw = blockIdx.x * 4 + wid;      // 8192 waves, 8 rows each
  float cw[8][8];
#pragma unroll
  for (int t = 0; t < 8; t++)
#pragma unroll
    for (int i = 0; i < 8; i++)
      cw[t][i] = c8w[i * 512 + t * 64 + lane];
  const float* xf = (const float*)x;
  const unsigned short* xh = (const unsigned short*)x;
  for (int r = gw * 8; r < gw * 8 + 8; r++) {
    float acc[8];
#pragma unroll
    for (int i = 0; i < 8; i++) acc[i] = 0.0f;
    if (isf) {
      const float* xr = xf + (size_t)r * 455;
#pragma unroll
      for (int t = 0; t < 8; t++) {
        int j = t * 64 + lane;
        float xv = (j < 455) ? xr[j] : 0.0f;
#pragma unroll
        for (int i = 0; i < 8; i++) acc[i] += xv * cw[t][i];
      }
    } else {
      const unsigned short* xr = xh + (size_t)r * 455;
#pragma unroll
      for (int t = 0; t < 8; t++) {
        int j = t * 64 + lane;
        float xv = (j < 455) ? bf2f(xr[j]) : 0.0f;
#pragma unroll
        for (int i = 0; i < 8; i++) acc[i] += xv * cw[t][i];
      }
    }
    // reduce within aligned 8-lane groups (offsets 1,2,4)
#pragma unroll
    for (int off = 1; off <= 4; off <<= 1)
#pragma unroll
      for (int i = 0; i < 8; i++) acc[i] += __shfl_xor(acc[i], off);
    // select acc[lane&7], then reduce across groups (offsets 8,16,32)
    int lg = lane & 7;
    float v = acc[0];
    v = (lg == 1) ? acc[1] : v;
    v = (lg == 2) ? acc[2] : v;
    v = (lg == 3) ? acc[3] : v;
    v = (lg == 4) ? acc[4] : v;
    v = (lg == 5) ? acc[5] : v;
    v = (lg == 6) ? acc[6] : v;
    v = (lg == 7) ? acc[7] : v;
    v += __shfl_xor(v, 8);
    v += __shfl_xor(v, 16);
    v += __shfl_xor(v, 32);
    if (lane < 8) {
      if (isf) ((float*)dout)[(size_t)r * 8 + lane] = v;
      else     ((unsigned short*)dout)[(size_t)r * 8 + lane] = f2bf(v);
    }
  }
}

// ---------------------------------------------------------------------------
// host
// ---------------------------------------------------------------------------
extern "C" void kernel_launch(void* const* d_in, const int* in_sizes, int n_in,
                              void* d_out, int out_size, void* d_ws, size_t ws_size,
                              hipStream_t stream) {
  const void* x    = d_in[0];
  const void* traj = d_in[1];
  const void* w1l0 = d_in[2];
  const void* w1l1 = d_in[3];
  W2Ptrs w2;
  for (int l = 0; l < 7; l++) w2.p[l] = d_in[4 + l];

  char* ws = (char*)d_ws;
  double* exps          = (double*)(ws + 0);                 // 336*169*8
  float* dint           = (float*)(ws + 458752);             // 10*2048*4
  float* c8w            = (float*)(ws + 540672);             // 8*512*4
  unsigned short* dwt   = (unsigned short*)(ws + 573440);    // 512*2048*2
  float* feat           = (float*)(ws + 2670592);            // 512*160*4
  unsigned short* sig   = (unsigned short*)(ws + 2998272);   // 8192*2048*2
  unsigned short* f2    = (unsigned short*)(ws + 36552704);  // 8192*512*2
  unsigned short* et    = (unsigned short*)(ws + 44941312);  // 512*8192*2
  float* cp             = (float*)(ws + 53329920);           // 8*512*512*4
  int* flag             = (int*)(ws + 61718528);

  SetupArgs sa; QWArgs qa;
  for (int i = 0; i < 16; i++) sa.angA[i] = 2.0 * M_PI * (double)i / 16.0;
  static const double XB[8] = {
    -0.9602898564975363, -0.7966664774136267, -0.5255324099163290,
    -0.1834346424956498,  0.1834346424956498,  0.5255324099163290,
     0.7966664774136267,  0.9602898564975363};
  static const double WBv[8] = {
     0.1012285362903763, 0.2223810344533745, 0.3137066458778873,
     0.3626837833783620, 0.3626837833783620, 0.3137066458778873,
     0.2223810344533745, 0.1012285362903763};
  for (int i = 0; i < 8; i++) { sa.angB[i] = acos(XB[i]); qa.wb[i] = WBv[i]; }
  for (int i = 0; i < 8; i++) {
    double th = 2.0 * M_PI * (double)i / 8.0;
    double Mm[3][3] = {{cos(th), sin(th), 0.0},
                       {-sin(th), cos(th), 0.0},
                       {0.0, 0.0, 1.0}};
    double x0 = Mm[0][1], x1 = Mm[1][1], x2 = Mm[2][1];
    double bb = acos(fmax(-1.0, fmin(1.0, x1)));
    double aa = atan2(x0, x2);
    double ca_ = cos(aa), sa_ = sin(aa), cb_ = cos(bb), sb_ = sin(bb);
    double MY[3][3] = {{ca_, 0, sa_}, {0, 1, 0}, {-sa_, 0, ca_}};
    double MX[3][3] = {{1, 0, 0}, {0, cb_, -sb_}, {0, sb_, cb_}};
    double P1[3][3], Rr[3][3];
    for (int r = 0; r < 3; r++)
      for (int c = 0; c < 3; c++) {
        double s = 0.0;
        for (int k = 0; k < 3; k++) s += MY[r][k] * MX[k][c];
        P1[r][c] = s;
      }
    for (int r = 0; r < 3; r++)
      for (int c = 0; c < 3; c++) {
        double s = 0.0;
        for (int k = 0; k < 3; k++) s += P1[k][r] * Mm[k][c];  // P1^T @ M
        Rr[r][c] = s;
      }
    double gg = atan2(Rr[0][2], Rr[0][0]);
    sa.c8a[i] = aa; sa.c8b[i] = bb; sa.c8g[i] = gg;
  }

  k_exps<<<337, 192, 0, stream>>>(sa, exps, x, flag);
  k_assemble<<<1379, 192, 0, stream>>>(exps, qa, dwt, dint, c8w,
                                       traj, w1l0, w1l1, feat, flag);
  k_post<<<8192, 256, 0, stream>>>(feat, dint, sig, w2, c8w, et, flag);
  k_gemm2<<<512, 256, 0, stream>>>(sig, dwt, f2);
  k_gemm3<<<512, 256, 0, stream>>>(f2, et, cp);
  k_xc8r<<<2304, 256, 0, stream>>>(x, c8w, cp, d_out, flag);
}

// Round 4
// 271.578 us; speedup vs baseline: 1.4072x; 1.2071x over previous
//
#include <hip/hip_runtime.h>
#include <hip/hip_bf16.h>
#include <math.h>

// ============================================================================
// EquiGroupSamplingC8 (f32 I/O confirmed by runtime sniff; bf16 path retained).
// R6: K1/K2 DP Wigner setup on fixed 13x13 padded matrices (unrolled).
// R8: K5/K6 3-buffer counted-vmcnt pipelines; K2 16 gammas/block.
// R9: k_post ebuild rebuilt: LDS-staged w2/c8w per (l,f,g-octet) block,
//     template<D> compile-time inner loops (regs + ds_read_b128), w2 read
//     from global exactly once. Pad-zero section. sig: 2 cols/thread with
//     float2 loads + packed uint stores.
// ============================================================================

typedef __attribute__((ext_vector_type(8))) short bf16x8;
typedef __attribute__((ext_vector_type(4))) float f32x4;
typedef __attribute__((ext_vector_type(16))) float f32x16;

__device__ const int c_offs[8] = {0, 1, 10, 35, 84, 165, 286, 455};

struct SetupArgs {
  double angA[16];              // 2*pi*k/16 (alpha and gamma grid)
  double angB[8];               // arccos(GL8 nodes)
  double c8a[8], c8b[8], c8g[8];
};
struct QWArgs { double wb[8]; };
struct W2Ptrs { const void* p[7]; };

__device__ __forceinline__ float bf2f(unsigned short u) {
  union { unsigned int i; float f; } v; v.i = ((unsigned int)u) << 16; return v.f;
}
__device__ __forceinline__ unsigned short f2bf(float f) {
  union { float f; unsigned int i; } v; v.f = f;
  unsigned int r = v.i + 0x7fffu + ((v.i >> 16) & 1u);
  return (unsigned short)(r >> 16);
}
__device__ __forceinline__ float in_val(const void* p, size_t i, int isf) {
  return isf ? ((const float*)p)[i] : bf2f(((const unsigned short*)p)[i]);
}
__device__ __forceinline__ void gl_lds16(const void* g, void* lds) {
  __builtin_amdgcn_global_load_lds(
      (const __attribute__((address_space(1))) unsigned int*)g,
      (__attribute__((address_space(3))) unsigned int*)lds, 16, 0, 0);
}

// ---------------------------------------------------------------------------
// K1: exp matrices, fixed 13x13 padded. blocks [0,336) = 7 l * 48 items;
// block 336 = dtype sniff. 192 threads, 1 element/thread, all loops unrolled.
// ---------------------------------------------------------------------------
__global__ __launch_bounds__(192) void k_exps(SetupArgs args, double* exps,
                                              const void* x, int* flag) {
  __shared__ double Qr[169], Qi[169], Bm[169], R[169];
  __shared__ double coefA[13], coefB[13], rowsum[13];
  __shared__ double snorm;
  __shared__ int cnt;
  int tid = threadIdx.x;

  if (blockIdx.x == 336) {           // dtype sniff: f32 N(0,1) magnitude band
    if (tid == 0) cnt = 0;
    __syncthreads();
    if (tid < 64) {
      float v = ((const float*)x)[tid];
      float a = fabsf(v);
      int ok = (v == v) && (a > 9.0949470e-13f) && (a < 1.0995116e12f);
      atomicAdd(&cnt, ok);
    }
    __syncthreads();
    if (tid == 0) *flag = (cnt >= 32) ? 1 : 0;
    return;
  }

  int l = blockIdx.x / 48, item = blockIdx.x % 48;
  int e = tid;
  bool val = (e < 169);
  int r = e / 13, c = e % 13;

  if (val) { Qr[e] = 0.0; Qi[e] = 0.0; }
  __syncthreads();
  if (tid == 0) {
    const double is2 = 0.70710678118654752440;
    for (int m = -l; m <= l; m++) {
      int rr = l + m;
      if (m < 0) {
        Qr[rr * 13 + (l - m)] = is2;
        Qi[rr * 13 + (l + m)] = -is2;
      } else if (m == 0) {
        Qr[l * 13 + l] = 1.0;
      } else {
        double s = (m & 1) ? -1.0 : 1.0;
        Qr[rr * 13 + (l + m)] = s * is2;
        Qi[rr * 13 + (l - m)] = s * is2;
      }
    }
  }
  double jj = (double)l;
  if (tid < 13) {  // hoisted ladder coefficients (clamped: padded rows are *0)
    double m1 = (double)(tid - 1 - l);
    coefA[tid] = -0.5 * sqrt(fmax(jj * (jj + 1.0) - m1 * (m1 + 1.0), 0.0));
    double m2 = (double)(tid + 1 - l);
    coefB[tid] = 0.5 * sqrt(fmax(jj * (jj + 1.0) - m2 * (m2 - 1.0), 0.0));
  }
  __syncthreads();
  { // multiply by (-1j)^l
    int lm = l & 3;
    double pr = (lm == 0) ? 1.0 : (lm == 2 ? -1.0 : 0.0);
    double pi = (lm == 1) ? -1.0 : (lm == 3 ? 1.0 : 0.0);
    if (val) {
      double qr = Qr[e], qi = Qi[e];
      Qr[e] = qr * pr - qi * pi;
      Qi[e] = qr * pi + qi * pr;
    }
  }
  __syncthreads();

  double t; int axis;
  if (item < 16)      { t = args.angA[item];      axis = 1; }
  else if (item < 24) { t = args.angB[item - 16]; axis = 0; }
  else if (item < 32) { t = args.c8a[item - 24];  axis = 1; }
  else if (item < 40) { t = args.c8b[item - 32];  axis = 0; }
  else                { t = args.c8g[item - 40];  axis = 1; }

  if (val) {
    double accr = 0.0;
    if (axis == 1) {
#pragma unroll
      for (int p = 0; p < 13; p++) {
        double mp = (double)(p - l);
        double ar = Qr[p * 13 + r], ai = -Qi[p * 13 + r];
        double br = Qr[p * 13 + c], bi = Qi[p * 13 + c];
        accr += -mp * (ar * bi + ai * br);
      }
    } else {
#pragma unroll
      for (int p = 0; p < 13; p++) {
        double xr = 0.0, xi = 0.0;
        if (p > 0) {
          double v = coefA[p];
          xr += v * Qr[(p - 1) * 13 + c]; xi += v * Qi[(p - 1) * 13 + c];
        }
        if (p < 12) {
          double v = coefB[p];
          xr += v * Qr[(p + 1) * 13 + c]; xi += v * Qi[(p + 1) * 13 + c];
        }
        double ar = Qr[p * 13 + r], ai = -Qi[p * 13 + r];
        accr += ar * xr - ai * xi;
      }
    }
    Bm[e] = t * accr;
  }
  __syncthreads();
  if (tid < 13) {  // parallel row-sums for the scaling norm
    double s = 0.0;
#pragma unroll
    for (int cc = 0; cc < 13; cc++) s += fabs(Bm[tid * 13 + cc]);
    rowsum[tid] = s;
  }
  __syncthreads();
  if (tid == 0) {
    double mx = 0.0;
#pragma unroll
    for (int rr = 0; rr < 13; rr++) mx = fmax(mx, rowsum[rr]);
    int s = 0;
    while (mx > 0.5 && s < 48) { mx *= 0.5; s++; }
    snorm = (double)s;
  }
  __syncthreads();
  int sq = (int)snorm;
  double sc = 1.0;
  for (int i = 0; i < sq; i++) sc *= 0.5;
  if (val) {
    double b = Bm[e] * sc;
    Bm[e] = b;
    R[e] = b / 16.0 + ((r == c) ? 1.0 : 0.0);
  }
  __syncthreads();
  for (int k = 15; k >= 1; k--) {   // Horner: R <- Bm*R/k + I
    double acc = 0.0;
    if (val) {
#pragma unroll
      for (int p = 0; p < 13; p++) acc += Bm[r * 13 + p] * R[p * 13 + c];
    }
    __syncthreads();
    if (val) R[e] = acc / (double)k + ((r == c) ? 1.0 : 0.0);
    __syncthreads();
  }
  for (int i = 0; i < sq; i++) {    // squarings
    double acc = 0.0;
    if (val) {
#pragma unroll
      for (int p = 0; p < 13; p++) acc += R[r * 13 + p] * R[p * 13 + c];
    }
    __syncthreads();
    if (val) R[e] = acc;
    __syncthreads();
  }
  double* out = exps + (size_t)blockIdx.x * 169;
  if (val) out[e] = R[e];
}

// ---------------------------------------------------------------------------
// K2: assemble (192 threads, fixed 13x13).
// blocks [0,896) = (l,a,b), 16 gammas each, register-buffered uint4 stores;
// [896,952) = (l,ci) c8 -> c8w f32; [952,1379) = feat (proj_1).
// ---------------------------------------------------------------------------
__global__ __launch_bounds__(192) void k_assemble(const double* exps, QWArgs qw,
                                                  unsigned short* dwt, float* dint,
                                                  float* c8w,
                                                  const void* traj, const void* w1l0,
                                                  const void* w1l1, float* feat,
                                                  const int* flag) {
  __shared__ double Ea[169], Eb[169], Ec[169], T1[169];
  int tid = threadIdx.x;
  int bx = blockIdx.x;

  if (bx >= 952) {                    // ---- feat (proj_1) ----
    int isf = __builtin_amdgcn_readfirstlane(flag[0]);
    int idx = (bx - 952) * 192 + tid;
    if (idx >= 512 * 160) return;
    int bt = idx / 160, rem = idx % 160;
    int c = rem / 10, i = rem % 10;
    float v;
    if (i == 0) {
      v = in_val(traj, bt * 10 + 9, isf) * in_val(w1l0, c, isf);
    } else {
      int ii = i - 1, w = ii / 3, m = ii % 3;
      float acc = 0.0f;
      for (int u = 0; u < 3; u++)
        acc += in_val(traj, bt * 10 + 3 * u + m, isf) *
               in_val(w1l1, c * 9 + u * 3 + w, isf);
      v = acc * 0.57735026918962576f;
    }
    feat[idx] = v;
    return;
  }

  int e = tid;
  bool valp = (e < 169);
  int r = e / 13, c = e % 13;

  if (bx >= 896) {                    // ---- C8 points ----
    int idx = bx - 896;
    int l = idx / 8, ci = idx % 8;
    int d = 2 * l + 1;
    const double* pa = exps + (size_t)(l * 48 + 24 + ci) * 169;
    const double* pb = exps + (size_t)(l * 48 + 32 + ci) * 169;
    const double* pc = exps + (size_t)(l * 48 + 40 + ci) * 169;
    if (valp) { Ea[e] = pa[e]; Eb[e] = pb[e]; Ec[e] = pc[e]; }
    __syncthreads();
    if (valp) {
      double acc = 0.0;
#pragma unroll
      for (int p = 0; p < 13; p++) acc += Ea[r * 13 + p] * Eb[p * 13 + c];
      T1[e] = acc;
    }
    __syncthreads();
    double scale = sqrt((double)(2 * l + 1));
    if (valp) {
      double acc = 0.0;
#pragma unroll
      for (int p = 0; p < 13; p++) acc += T1[r * 13 + p] * Ec[p * 13 + c];
      if (r < d && c < d)
        c8w[ci * 512 + c_offs[l] + r * d + c] = (float)(scale * acc);
    }
    if (l == 0) {
      for (int jz = 455 + tid; jz < 512; jz += 192)
        c8w[ci * 512 + jz] = 0.0f;
    }
    return;
  }

  // ---- grid (l, a, b), all 16 gammas in-register ----
  int l = bx >> 7, rem = bx & 127;
  int a = rem >> 3, b = rem & 7;
  int d = 2 * l + 1;
  const double* pa = exps + (size_t)(l * 48 + a) * 169;
  const double* pb = exps + (size_t)(l * 48 + 16 + b) * 169;
  if (valp) { Ea[e] = pa[e]; Eb[e] = pb[e]; }
  __syncthreads();
  if (valp) {
    double acc = 0.0;
#pragma unroll
    for (int p = 0; p < 13; p++) acc += Ea[r * 13 + p] * Eb[p * 13 + c];
    T1[e] = acc;
  }
  double scale = sqrt((double)(2 * l + 1));
  double qwv = qw.wb[b] * (1.0 / 512.0);
  bool inblk = valp && (r < d) && (c < d);
  int j = inblk ? (c_offs[l] + r * d + c) : 0;
  int g0 = a * 128 + b * 16;
  const double* ctab = exps + (size_t)(l * 48) * 169;   // items [0,16) = gamma
  unsigned int ow[8];
  float dv[16];
#pragma unroll
  for (int cc = 0; cc < 16; cc++) {
    __syncthreads();
    if (valp) Ec[e] = ctab[(size_t)cc * 169 + e];
    __syncthreads();
    double acc = 0.0;
    if (valp) {
#pragma unroll
      for (int p = 0; p < 13; p++) acc += T1[r * 13 + p] * Ec[p * 13 + c];
    }
    unsigned int hv = (unsigned int)f2bf((float)(scale * acc * qwv));
    if ((cc & 1) == 0) ow[cc >> 1] = hv;
    else               ow[cc >> 1] |= hv << 16;
    dv[cc] = (float)(scale * acc);
  }
  if (inblk) {
    unsigned short* wp = &dwt[(size_t)j * 2048 + g0];
    *(uint4*)&wp[0] = make_uint4(ow[0], ow[1], ow[2], ow[3]);
    *(uint4*)&wp[8] = make_uint4(ow[4], ow[5], ow[6], ow[7]);
    if (l == 1) {
      float* dp = &dint[(size_t)(1 + r * 3 + c) * 2048 + g0];
      *(float4*)&dp[0]  = make_float4(dv[0],  dv[1],  dv[2],  dv[3]);
      *(float4*)&dp[4]  = make_float4(dv[4],  dv[5],  dv[6],  dv[7]);
      *(float4*)&dp[8]  = make_float4(dv[8],  dv[9],  dv[10], dv[11]);
      *(float4*)&dp[12] = make_float4(dv[12], dv[13], dv[14], dv[15]);
    }
    if (l == 0) {
      float* dp = &dint[g0];
      *(float4*)&dp[0]  = make_float4(dv[0],  dv[1],  dv[2],  dv[3]);
      *(float4*)&dp[4]  = make_float4(dv[4],  dv[5],  dv[6],  dv[7]);
      *(float4*)&dp[8]  = make_float4(dv[8],  dv[9],  dv[10], dv[11]);
      *(float4*)&dp[12] = make_float4(dv[12], dv[13], dv[14], dv[15]);
    }
  }
  if (l == 0 && tid < 57) {          // zero rows 455..511 for this g-band
    unsigned short* zp = &dwt[(size_t)(455 + tid) * 2048 + g0];
    *(uint4*)&zp[0] = make_uint4(0, 0, 0, 0);
    *(uint4*)&zp[8] = make_uint4(0, 0, 0, 0);
  }
}

// ---------------------------------------------------------------------------
// k_post: blocks [0,896) = ebuild (LDS-staged, template<D>);
//         [896,1408) = et pad-zero; [1408,3456) = sig.
// ---------------------------------------------------------------------------
template <int D>
__device__ __forceinline__ void ebuild_body(int f, int g0, const void* wp,
                                            const float* c8w, unsigned short* et,
                                            int isf, int offs,
                                            float* w2s, float* c8p) {
  const int d2 = D * D;
  int tid = threadIdx.x;
  // stage w2 slice: 8 g-rows x d2, contiguous in global; LDS rows padded to 16
  size_t gbase = ((size_t)f * 64 + g0) * d2;
  for (int e = tid; e < 8 * d2; e += 256) {
    int r = e / D, w = e - r * D;            // r = g*D+u
    w2s[r * 16 + w] = in_val(wp, gbase + e, isf);
  }
  // stage c8: [8 i][D w][16 pad m]
  for (int e = tid; e < 8 * d2; e += 256) {
    int i = e / d2, k = e - i * d2;
    int w = k / D, m = k - w * D;
    c8p[(i * D + w) * 16 + m] = c8w[i * 512 + offs + k];
  }
  __syncthreads();
  const float rs = rsqrtf((float)(16 * D));
  for (int R = tid; R < 64 * D; R += 256) {  // R = (g*8+i)*D + u
    int gi = R / D, u = R - gi * D;
    int g = gi >> 3, i = gi & 7;
    float wrow[D];
#pragma unroll
    for (int w = 0; w < D; w++) wrow[w] = w2s[(g * D + u) * 16 + w];
    float accv[D];
#pragma unroll
    for (int m = 0; m < D; m++) accv[m] = 0.0f;
#pragma unroll
    for (int w = 0; w < D; w++)
#pragma unroll
      for (int m = 0; m < D; m++)
        accv[m] += wrow[w] * c8p[(i * D + w) * 16 + m];
    unsigned short* orow =
        &et[(size_t)((g0 + g) * 8 + i) * 8192 + f * 512 + offs + u * D];
#pragma unroll
    for (int m = 0; m < D; m++) orow[m] = f2bf(accv[m] * rs);
  }
}

__global__ __launch_bounds__(256) void k_post(const float* feat, const float* dint,
                                              unsigned short* sig, W2Ptrs w2,
                                              const float* c8w, unsigned short* et,
                                              const int* flag) {
  __shared__ float w2s[1664], c8p[1664];
  int bx = blockIdx.x;
  int tid = threadIdx.x;

  if (bx < 896) {                     // ---- ebuild ----
    int isf = __builtin_amdgcn_readfirstlane(flag[0]);
    int li = bx >> 7;                 // 0..6, big l first
    int l = 6 - li;
    int rem = bx & 127;
    int f = rem >> 3, g0 = (rem & 7) * 8;
    int offs = c_offs[l];
    const void* wp = w2.p[0];
    wp = (l >= 1) ? w2.p[1] : wp;
    wp = (l >= 2) ? w2.p[2] : wp;
    wp = (l >= 3) ? w2.p[3] : wp;
    wp = (l >= 4) ? w2.p[4] : wp;
    wp = (l >= 5) ? w2.p[5] : wp;
    wp = (l >= 6) ? w2.p[6] : wp;
    switch (l) {
      case 6: ebuild_body<13>(f, g0, wp, c8w, et, isf, offs, w2s, c8p); break;
      case 5: ebuild_body<11>(f, g0, wp, c8w, et, isf, offs, w2s, c8p); break;
      case 4: ebuild_body<9>(f, g0, wp, c8w, et, isf, offs, w2s, c8p); break;
      case 3: ebuild_body<7>(f, g0, wp, c8w, et, isf, offs, w2s, c8p); break;
      case 2: ebuild_body<5>(f, g0, wp, c8w, et, isf, offs, w2s, c8p); break;
      case 1: ebuild_body<3>(f, g0, wp, c8w, et, isf, offs, w2s, c8p); break;
      default: ebuild_body<1>(f, g0, wp, c8w, et, isf, offs, w2s, c8p); break;
    }
    return;
  }

  if (bx < 1408) {                    // ---- et pad-zero (jj in [455,512)) ----
    int n = bx - 896;                 // [0,512)
    int f = tid >> 4, k = tid & 15;
#pragma unroll
    for (int s = 0; s < 4; s++) {
      int jj = 455 + k + s * 16;
      if (jj < 512) et[(size_t)n * 8192 + f * 512 + jj] = 0;
    }
    return;
  }

  // ---- sig = relu(feat @ D_IN^T)*sqrt2; 2 cols/thread ----
  int bx2 = bx - 1408;                // [0,2048)
  int bi = bx2 >> 2;
  int g0 = ((bx2 & 3) << 9) + tid * 2;
  float din0[10], din1[10];
#pragma unroll
  for (int i = 0; i < 10; i++) {
    float2 dv = *(const float2*)&dint[(size_t)i * 2048 + g0];
    din0[i] = dv.x; din1[i] = dv.y;
  }
  const float* fr = feat + bi * 160;
  for (int cc = 0; cc < 16; cc++) {
    float a0 = 0.0f, a1 = 0.0f;
#pragma unroll
    for (int i = 0; i < 10; i++) {
      float fv = fr[cc * 10 + i];
      a0 += fv * din0[i];
      a1 += fv * din1[i];
    }
    a0 = fmaxf(a0, 0.0f) * 1.41421356237309505f;
    a1 = fmaxf(a1, 0.0f) * 1.41421356237309505f;
    unsigned int pk = (unsigned int)f2bf(a0) | ((unsigned int)f2bf(a1) << 16);
    *(unsigned int*)&sig[(size_t)(bi * 16 + cc) * 2048 + g0] = pk;
  }
}

// ---------------------------------------------------------------------------
// K5: GEMM2: f2[8192][512] = sig[8192][2048] @ dwt^T.
// BM=128 BN=64 BK=64, 32x32x16 MFMA, XOR-swizzled LDS, 3-buffer counted-vmcnt
// pipeline: stage kt+2 after compute kt; s_waitcnt vmcnt(6) (not 0) + one
// s_barrier per K-step, so 2 stages stay in flight across the barrier.
// ---------------------------------------------------------------------------
__global__ __launch_bounds__(256) void k_gemm2(const unsigned short* A,
                                               const unsigned short* B,
                                               unsigned short* C) {
  __shared__ __align__(16) unsigned short As[3][128 * 64];
  __shared__ __align__(16) unsigned short Bs[3][64 * 64];
  int tid = threadIdx.x;
  int lane = tid & 63, wid = tid >> 6;
  int xcd = blockIdx.x & 7, bi = blockIdx.x >> 3;
  int mt = xcd * 8 + (bi >> 3), nt = bi & 7;
  int m0 = mt * 128, n0 = nt * 64;
  int wm = wid >> 1, wn = wid & 1;
  f32x16 acc[2];
#pragma unroll
  for (int t = 0; t < 2; t++)
#pragma unroll
    for (int r = 0; r < 16; r++) acc[t][r] = 0.0f;

  int r0 = tid >> 3;
  int kcl = (tid & 7) ^ (r0 & 7);          // logical k-chunk this lane fetches
  const unsigned short* Abase = A + (size_t)m0 * 2048;
  const unsigned short* Bbase = B + (size_t)n0 * 2048;
  int mrow = (lane & 31);
  int xr = lane & 7;
  int khalf = lane >> 5;

  auto STAGE = [&](int buf, int kt) {
    int k0 = kt * 64;
#pragma unroll
    for (int i = 0; i < 4; i++)
      gl_lds16(Abase + (size_t)(i * 32 + r0) * 2048 + k0 + kcl * 8,
               &As[buf][i * 2048 + wid * 512]);
#pragma unroll
    for (int i = 0; i < 2; i++)
      gl_lds16(Bbase + (size_t)(i * 32 + r0) * 2048 + k0 + kcl * 8,
               &Bs[buf][i * 2048 + wid * 512]);
  };

  STAGE(0, 0);
  STAGE(1, 1);
  int cb = 0;
  for (int kt = 0; kt < 32; kt++) {
    if (kt < 31) asm volatile("s_waitcnt vmcnt(6)" ::: "memory");
    else         asm volatile("s_waitcnt vmcnt(0)" ::: "memory");
    __builtin_amdgcn_s_barrier();
    __builtin_amdgcn_sched_barrier(0);
    const unsigned short* Ab = As[cb];
    const unsigned short* Bb = Bs[cb];
#pragma unroll
    for (int q = 0; q < 4; q++) {           // K quarters of 16
      int qc = q * 2 + khalf;               // logical k-chunk [0,8)
      bf16x8 bv = *(const bf16x8*)&Bb[(wn * 32 + mrow) * 64 + (qc ^ xr) * 8];
#pragma unroll
      for (int t = 0; t < 2; t++) {
        bf16x8 av = *(const bf16x8*)&Ab[(wm * 64 + t * 32 + mrow) * 64 + (qc ^ xr) * 8];
        acc[t] = __builtin_amdgcn_mfma_f32_32x32x16_bf16(av, bv, acc[t], 0, 0, 0);
      }
    }
    if (kt < 30) STAGE(cb == 0 ? 2 : cb - 1, kt + 2);
    cb = (cb == 2) ? 0 : cb + 1;
  }
  int col = n0 + wn * 32 + (lane & 31);
#pragma unroll
  for (int t = 0; t < 2; t++)
#pragma unroll
    for (int r = 0; r < 16; r++) {
      int row = m0 + wm * 64 + t * 32 + (r & 3) + 8 * (r >> 2) + 4 * (lane >> 5);
      C[(size_t)row * 512 + col] = f2bf(acc[t][r]);
    }
}

// ---------------------------------------------------------------------------
// K6: GEMM3 split-K=8: Cp[kc][512][512] f32 = f2[512][8192] @ E (E_T staged).
// BM=64 BN=64 (grid 512, 2 blocks/CU), 3-buffer counted-vmcnt pipeline.
// ---------------------------------------------------------------------------
__global__ __launch_bounds__(256) void k_gemm3(const unsigned short* A,
                                               const unsigned short* B, float* Cp) {
  __shared__ __align__(16) unsigned short As[3][64 * 32];
  __shared__ __align__(16) unsigned short Bs[3][64 * 32];
  int tid = threadIdx.x, lane = tid & 63, wid = tid >> 6;
  int kc = blockIdx.x >> 6, mt = (blockIdx.x >> 3) & 7, nt = blockIdx.x & 7;
  int m0 = mt * 64, n0 = nt * 64;
  int wm = wid >> 1, wn = wid & 1;
  f32x4 acc[2][2];
#pragma unroll
  for (int a = 0; a < 2; a++)
#pragma unroll
    for (int b = 0; b < 2; b++) acc[a][b] = (f32x4){0.f, 0.f, 0.f, 0.f};
  int ar = tid >> 2, ak = (tid & 3) * 8;
  const unsigned short* Abase = A + (size_t)m0 * 8192 + kc * 1024;
  const unsigned short* Bbase = B + (size_t)n0 * 8192 + kc * 1024;
  int row = lane & 15, kq = (lane >> 4) * 8;

  auto STAGE = [&](int buf, int kt) {
    int k0 = kt * 32;
    gl_lds16(Abase + (size_t)ar * 8192 + k0 + ak, &As[buf][wid * 512]);
    gl_lds16(Bbase + (size_t)ar * 8192 + k0 + ak, &Bs[buf][wid * 512]);
  };

  STAGE(0, 0);
  STAGE(1, 1);
  int cb = 0;
  for (int kt = 0; kt < 32; kt++) {
    if (kt < 31) asm volatile("s_waitcnt vmcnt(2)" ::: "memory");
    else         asm volatile("s_waitcnt vmcnt(0)" ::: "memory");
    __builtin_amdgcn_s_barrier();
    __builtin_amdgcn_sched_barrier(0);
    bf16x8 af[2], bfr[2];
#pragma unroll
    for (int im = 0; im < 2; im++)
      af[im] = *(const bf16x8*)&As[cb][(wm * 32 + im * 16 + row) * 32 + kq];
#pragma unroll
    for (int in = 0; in < 2; in++)
      bfr[in] = *(const bf16x8*)&Bs[cb][(wn * 32 + in * 16 + row) * 32 + kq];
#pragma unroll
    for (int im = 0; im < 2; im++)
#pragma unroll
      for (int in = 0; in < 2; in++)
        acc[im][in] = __builtin_amdgcn_mfma_f32_16x16x32_bf16(af[im], bfr[in],
                                                              acc[im][in], 0, 0, 0);
    if (kt < 30) STAGE(cb == 0 ? 2 : cb - 1, kt + 2);
    cb = (cb == 2) ? 0 : cb + 1;
  }
  int col = lane & 15, rq = (lane >> 4) * 4;
  float* out = Cp + (size_t)kc * 262144;
#pragma unroll
  for (int im = 0; im < 2; im++)
#pragma unroll
    for (int in = 0; in < 2; in++)
#pragma unroll
      for (int r = 0; r < 4; r++) {
        int rr = m0 + wm * 32 + im * 16 + rq + r;
        int cc = n0 + wn * 32 + in * 16 + col;
        out[(size_t)rr * 512 + cc] = acc[im][in][r];
      }
}

// ---------------------------------------------------------------------------
// K7: blocks [0,2048): x_c8 = x @ C8W^T (wave per 8 rows, 27-shuffle reduce).
//     blocks [2048,2304): split-K reduce -> traj_c8.
// ---------------------------------------------------------------------------
__global__ __launch_bounds__(256) void k_xc8r(const void* x, const float* c8w,
                                              const float* Cp, void* dout,
                                              const int* flag) {
  int tid = threadIdx.x, lane = tid & 63, wid = tid >> 6;
  int isf = __builtin_amdgcn_readfirstlane(flag[0]);

  if (blockIdx.x >= 2048) {           // ---- split-K reduce ----
    int idx = (blockIdx.x - 2048) * 256 + tid;   // [0, 65536)
    const float4* c = (const float4*)Cp;
    float s0 = 0.f, s1 = 0.f, s2 = 0.f, s3 = 0.f;
#pragma unroll
    for (int p = 0; p < 8; p++) {
      float4 v = c[idx + p * 65536];
      s0 += v.x; s1 += v.y; s2 += v.z; s3 += v.w;
    }
    size_t base = 524288 + (size_t)idx * 4;
    if (isf) {
      float4 o; o.x = s0; o.y = s1; o.z = s2; o.w = s3;
      *(float4*)((float*)dout + base) = o;
    } else {
      unsigned int p0 = (unsigned int)f2bf(s0) | ((unsigned int)f2bf(s1) << 16);
      unsigned int p1 = (unsigned int)f2bf(s2) | ((unsigned int)f2bf(s3) << 16);
      uint2 pk; pk.x = p0; pk.y = p1;
      *(uint2*)((unsigned short*)dout + base) = pk;
    }
    return;
  }

  // ---- x_c8: wave per 8 rows, lane j covers col band ----
  int gw = blockIdx.x * 4 + wid;      // 8192 waves, 8 rows each
  float cw[8][8];
#pragma unroll
  for (int t = 0; t < 8; t++)
#pragma unroll
    for (int i = 0; i < 8; i++)
      cw[t][i] = c8w[i * 512 + t * 64 + lane];
  const float* xf = (const float*)x;
  const unsigned short* xh = (const unsigned short*)x;
  for (int r = gw * 8; r < gw * 8 + 8; r++) {
    float acc[8];
#pragma unroll
    for (int i = 0; i < 8; i++) acc[i] = 0.0f;
    if (isf) {
      const float* xr = xf + (size_t)r * 455;
#pragma unroll
      for (int t = 0; t < 8; t++) {
        int j = t * 64 + lane;
        float xv = (j < 455) ? xr[j] : 0.0f;
#pragma unroll
        for (int i = 0; i < 8; i++) acc[i] += xv * cw[t][i];
      }
    } else {
      const unsigned short* xr = xh + (size_t)r * 455;
#pragma unroll
      for (int t = 0; t < 8; t++) {
        int j = t * 64 + lane;
        float xv = (j < 455) ? bf2f(xr[j]) : 0.0f;
#pragma unroll
        for (int i = 0; i < 8; i++) acc[i] += xv * cw[t][i];
      }
    }
    // reduce within aligned 8-lane groups (offsets 1,2,4)
#pragma unroll
    for (int off = 1; off <= 4; off <<= 1)
#pragma unroll
      for (int i = 0; i < 8; i++) acc[i] += __shfl_xor(acc[i], off);
    // select acc[lane&7], then reduce across groups (offsets 8,16,32)
    int lg = lane & 7;
    float v = acc[0];
    v = (lg == 1) ? acc[1] : v;
    v = (lg == 2) ? acc[2] : v;
    v = (lg == 3) ? acc[3] : v;
    v = (lg == 4) ? acc[4] : v;
    v = (lg == 5) ? acc[5] : v;
    v = (lg == 6) ? acc[6] : v;
    v = (lg == 7) ? acc[7] : v;
    v += __shfl_xor(v, 8);
    v += __shfl_xor(v, 16);
    v += __shfl_xor(v, 32);
    if (lane < 8) {
      if (isf) ((float*)dout)[(size_t)r * 8 + lane] = v;
      else     ((unsigned short*)dout)[(size_t)r * 8 + lane] = f2bf(v);
    }
  }
}

// ---------------------------------------------------------------------------
// host
// ---------------------------------------------------------------------------
extern "C" void kernel_launch(void* const* d_in, const int* in_sizes, int n_in,
                              void* d_out, int out_size, void* d_ws, size_t ws_size,
                              hipStream_t stream) {
  const void* x    = d_in[0];
  const void* traj = d_in[1];
  const void* w1l0 = d_in[2];
  const void* w1l1 = d_in[3];
  W2Ptrs w2;
  for (int l = 0; l < 7; l++) w2.p[l] = d_in[4 + l];

  char* ws = (char*)d_ws;
  double* exps          = (double*)(ws + 0);                 // 336*169*8
  float* dint           = (float*)(ws + 458752);             // 10*2048*4
  float* c8w            = (float*)(ws + 540672);             // 8*512*4
  unsigned short* dwt   = (unsigned short*)(ws + 573440);    // 512*2048*2
  float* feat           = (float*)(ws + 2670592);            // 512*160*4
  unsigned short* sig   = (unsigned short*)(ws + 2998272);   // 8192*2048*2
  unsigned short* f2    = (unsigned short*)(ws + 36552704);  // 8192*512*2
  unsigned short* et    = (unsigned short*)(ws + 44941312);  // 512*8192*2
  float* cp             = (float*)(ws + 53329920);           // 8*512*512*4
  int* flag             = (int*)(ws + 61718528);

  SetupArgs sa; QWArgs qa;
  for (int i = 0; i < 16; i++) sa.angA[i] = 2.0 * M_PI * (double)i / 16.0;
  static const double XB[8] = {
    -0.9602898564975363, -0.7966664774136267, -0.5255324099163290,
    -0.1834346424956498,  0.1834346424956498,  0.5255324099163290,
     0.7966664774136267,  0.9602898564975363};
  static const double WBv[8] = {
     0.1012285362903763, 0.2223810344533745, 0.3137066458778873,
     0.3626837833783620, 0.3626837833783620, 0.3137066458778873,
     0.2223810344533745, 0.1012285362903763};
  for (int i = 0; i < 8; i++) { sa.angB[i] = acos(XB[i]); qa.wb[i] = WBv[i]; }
  for (int i = 0; i < 8; i++) {
    double th = 2.0 * M_PI * (double)i / 8.0;
    double Mm[3][3] = {{cos(th), sin(th), 0.0},
                       {-sin(th), cos(th), 0.0},
                       {0.0, 0.0, 1.0}};
    double x0 = Mm[0][1], x1 = Mm[1][1], x2 = Mm[2][1];
    double bb = acos(fmax(-1.0, fmin(1.0, x1)));
    double aa = atan2(x0, x2);
    double ca_ = cos(aa), sa_ = sin(aa), cb_ = cos(bb), sb_ = sin(bb);
    double MY[3][3] = {{ca_, 0, sa_}, {0, 1, 0}, {-sa_, 0, ca_}};
    double MX[3][3] = {{1, 0, 0}, {0, cb_, -sb_}, {0, sb_, cb_}};
    double P1[3][3], Rr[3][3];
    for (int r = 0; r < 3; r++)
      for (int c = 0; c < 3; c++) {
        double s = 0.0;
        for (int k = 0; k < 3; k++) s += MY[r][k] * MX[k][c];
        P1[r][c] = s;
      }
    for (int r = 0; r < 3; r++)
      for (int c = 0; c < 3; c++) {
        double s = 0.0;
        for (int k = 0; k < 3; k++) s += P1[k][r] * Mm[k][c];  // P1^T @ M
        Rr[r][c] = s;
      }
    double gg = atan2(Rr[0][2], Rr[0][0]);
    sa.c8a[i] = aa; sa.c8b[i] = bb; sa.c8g[i] = gg;
  }

  k_exps<<<337, 192, 0, stream>>>(sa, exps, x, flag);
  k_assemble<<<1379, 192, 0, stream>>>(exps, qa, dwt, dint, c8w,
                                       traj, w1l0, w1l1, feat, flag);
  k_post<<<3456, 256, 0, stream>>>(feat, dint, sig, w2, c8w, et, flag);
  k_gemm2<<<512, 256, 0, stream>>>(sig, dwt, f2);
  k_gemm3<<<512, 256, 0, stream>>>(f2, et, cp);
  k_xc8r<<<2304, 256, 0, stream>>>(x, c8w, cp, d_out, flag);
}